// Round 9
// baseline (238.310 us; speedup 1.0000x reference)
//
#include <hip/hip_runtime.h>

// Problem constants (CompactCrossAttention)
#define Bb   2
#define QL   1024
#define KL   4096
#define Hh   1024
#define NH   16
#define HD   64

#define KSPLIT 2
#define CHUNK  (KL / KSPLIT)   // 2048 keys per block
#define NTM    (CHUNK / 128)   // 16 macro-tiles of 128 keys

typedef unsigned short u16;
typedef __attribute__((ext_vector_type(8))) short bf16x8;   // MFMA A/B frag
typedef __attribute__((ext_vector_type(8))) unsigned short usv8;
typedef __attribute__((ext_vector_type(4))) float f32x4;    // MFMA C/D frag

#define QSCALE 0.1803368801111204f   // 0.125 * log2(e): scores in log2 domain
#define RTHR   11.0f                 // defer-max threshold (log2 units)

__device__ __forceinline__ u16 f2bf(float f) {
    union { float f; unsigned int u; } v; v.f = f;
    unsigned int r = (v.u + 0x7FFFu + ((v.u >> 16) & 1u)) >> 16;
    return (u16)r;
}

__device__ __forceinline__ unsigned int cvt_pk_bf16(float lo, float hi) {
    unsigned int r;
    asm("v_cvt_pk_bf16_f32 %0, %1, %2" : "=v"(r) : "v"(lo), "v"(hi));
    return r;
}

__device__ __forceinline__ float max3f(float a, float b, float c) {
    float r;
    asm("v_max3_f32 %0, %1, %2, %3" : "=v"(r) : "v"(a), "v"(b), "v"(c));
    return r;
}

__device__ __forceinline__ void gload16(const void* g, void* l) {
    __builtin_amdgcn_global_load_lds(
        (const __attribute__((address_space(1))) void*)g,
        (__attribute__((address_space(3))) void*)l, 16, 0, 0);
}

// pack 8 fp32 -> 8 bf16 (uint4)
__device__ __forceinline__ uint4 pack8(const float4& f0, const float4& f1) {
    uint4 o;
    o.x = cvt_pk_bf16(f0.x, f0.y);
    o.y = cvt_pk_bf16(f0.z, f0.w);
    o.z = cvt_pk_bf16(f1.x, f1.y);
    o.w = cvt_pk_bf16(f1.z, f1.w);
    return o;
}

// ---------------------------------------------------------------------------
// All three weight transposes (fp32 [R][C] -> bf16 [C][R]) in ONE launch.
// Output rows GRANULE-SWIZZLED: logical k-granule gl at slot gl ^ (n&7).
// ---------------------------------------------------------------------------
__global__ __launch_bounds__(256) void wtrans_all(const float* __restrict__ wq,
                                                  const float* __restrict__ wkv,
                                                  const float* __restrict__ wout,
                                                  u16* __restrict__ wqT,
                                                  u16* __restrict__ wkvT,
                                                  u16* __restrict__ woutT) {
    __shared__ float T[64][65];
    int bid = blockIdx.x;
    const float* in; u16* out; int C;
    if (bid < 256)      { in = wq;   out = wqT;   C = 1024; }
    else if (bid < 768) { in = wkv;  out = wkvT;  C = 2048; bid -= 256; }
    else                { in = wout; out = woutT; C = 1024; bid -= 768; }
    const int nc = C >> 6;
    const int c0 = (bid % nc) * 64;
    const int r0 = (bid / nc) * 64;
    const int t  = threadIdx.x;
    const int tx = t & 15, ty = t >> 4;
#pragma unroll
    for (int p = 0; p < 4; ++p) {
        const int r = ty + p * 16;
        float4 v = *reinterpret_cast<const float4*>(in + (size_t)(r0 + r) * C + c0 + tx * 4);
        T[r][tx * 4 + 0] = v.x; T[r][tx * 4 + 1] = v.y;
        T[r][tx * 4 + 2] = v.z; T[r][tx * 4 + 3] = v.w;
    }
    __syncthreads();
#pragma unroll
    for (int p = 0; p < 4; ++p) {
        const int c = ty + p * 16;
        const int n = c0 + c;
        ushort4 o;
        o.x = f2bf(T[tx * 4 + 0][c]); o.y = f2bf(T[tx * 4 + 1][c]);
        o.z = f2bf(T[tx * 4 + 2][c]); o.w = f2bf(T[tx * 4 + 3][c]);
        const int kb   = r0 + tx * 4;
        const int kout = (kb & ~63) | ((((kb >> 3) & 7) ^ (n & 7)) << 3) | (kb & 7);
        *reinterpret_cast<ushort4*>(out + (size_t)n * 1024 + kout) = o;
    }
}

// ---------------------------------------------------------------------------
// Q projection GEMM: Qb = QSCALE * (query_f32 @ wqT^T).  BMT=64.
// ---------------------------------------------------------------------------
__global__ __launch_bounds__(256) void qgemm(const float* __restrict__ A32,
                                             const u16* __restrict__ Bt,
                                             u16* __restrict__ C) {
    __shared__ u16 As[64 * 64];
    __shared__ u16 Bs[128 * 64];
    const int nwg = gridDim.x * gridDim.y;
    const int id  = blockIdx.y * gridDim.x + blockIdx.x;
    const int sw  = (id & 7) * (nwg >> 3) + (id >> 3);   // chunked per-XCD
    const int bx  = sw % gridDim.x, by = sw / gridDim.x;
    const int tid = threadIdx.x, lane = tid & 63, w = tid >> 6;
    const int wr = w >> 1, wc = w & 1;
    const int row0 = by * 64, col0 = bx * 128;
    const int MROW = wr * 32;
    const int x7   = lane & 7;

    f32x4 acc[2][4];
#pragma unroll
    for (int m = 0; m < 2; ++m)
#pragma unroll
        for (int n = 0; n < 4; ++n) acc[m][n] = (f32x4){0.f, 0.f, 0.f, 0.f};

    const int lrow = lane >> 3, lcol = (lane & 7) * 8;
    const int arow = tid >> 3, acol8 = (tid & 7) * 8;
    const int aphys = acol8 ^ ((arow & 7) << 3);

    for (int k0 = 0; k0 < 1024; k0 += 64) {
        __syncthreads();
#pragma unroll
        for (int p = 0; p < 2; ++p) {
            const int r = p * 32 + arow;
            const float* src = A32 + (size_t)(row0 + r) * 1024 + k0 + acol8;
            float4 f0 = *reinterpret_cast<const float4*>(src);
            float4 f1 = *reinterpret_cast<const float4*>(src + 4);
            *reinterpret_cast<uint4*>(&As[r * 64 + aphys]) = pack8(f0, f1);
        }
#pragma unroll
        for (int p = 0; p < 4; ++p) {
            const int base = w * 512 + p * 2048;
            const int row  = (base >> 6) + lrow;
            gload16(Bt + (size_t)(col0 + row) * 1024 + k0 + lcol, &Bs[base]);
        }
        __syncthreads();
#pragma unroll
        for (int kk = 0; kk < 2; ++kk) {
            bf16x8 af[2], bfr[4];
            const int G = ((kk * 4 + (lane >> 4)) ^ x7) * 8;
#pragma unroll
            for (int m = 0; m < 2; ++m)
                af[m] = *reinterpret_cast<const bf16x8*>(
                    &As[(MROW + m * 16 + (lane & 15)) * 64 + G]);
#pragma unroll
            for (int n = 0; n < 4; ++n)
                bfr[n] = *reinterpret_cast<const bf16x8*>(
                    &Bs[(wc * 64 + n * 16 + (lane & 15)) * 64 + G]);
#pragma unroll
            for (int m = 0; m < 2; ++m)
#pragma unroll
                for (int n = 0; n < 4; ++n)
                    acc[m][n] = __builtin_amdgcn_mfma_f32_16x16x32_bf16(
                        af[m], bfr[n], acc[m][n], 0, 0, 0);
        }
    }
#pragma unroll
    for (int m = 0; m < 2; ++m)
#pragma unroll
        for (int n = 0; n < 4; ++n) {
            const int gc = col0 + wc * 64 + n * 16 + (lane & 15);
#pragma unroll
            for (int r = 0; r < 4; ++r) {
                const int gr = row0 + MROW + m * 16 + (lane >> 4) * 4 + r;
                C[(size_t)gr * 1024 + gc] = f2bf(acc[m][n][r] * QSCALE);
            }
        }
}

// ---------------------------------------------------------------------------
// KV projection GEMM -> pre-swizzled K/V blobs.  BMT=128.
// NEW: A-operand register pipeline — next k-step's fp32 loads are issued
// during this step's staging and hidden under the MFMA phase (raw barriers +
// counted vmcnt(8): B's 4 gload_lds landed, 8 A-loads still flying).
// ---------------------------------------------------------------------------
__global__ __launch_bounds__(256, 4) void kvgemm(const float* __restrict__ A32,
                                                 const u16* __restrict__ Bt,
                                                 u16* __restrict__ KT,
                                                 u16* __restrict__ VT) {
    __shared__ u16 As[128 * 64];
    __shared__ u16 Bs[128 * 64];
    const int nwg = gridDim.x * gridDim.y;
    const int id  = blockIdx.y * gridDim.x + blockIdx.x;
    const int sw  = (id & 7) * (nwg >> 3) + (id >> 3);
    const int bx  = sw % gridDim.x, by = sw / gridDim.x;
    const int tid = threadIdx.x, lane = tid & 63, w = tid >> 6;
    const int wr = w >> 1, wc = w & 1;
    const int row0 = by * 128, col0 = bx * 128;
    const int MROW = wr * 64;
    const int x7   = lane & 7;

    f32x4 acc[4][4];
#pragma unroll
    for (int m = 0; m < 4; ++m)
#pragma unroll
        for (int n = 0; n < 4; ++n) acc[m][n] = (f32x4){0.f, 0.f, 0.f, 0.f};

    const int lrow = lane >> 3, lcol = (lane & 7) * 8;
    const int arow = tid >> 3, acol8 = (tid & 7) * 8;
    const int aphys = acol8 ^ ((arow & 7) << 3);
    const float* abase = A32 + (size_t)(row0 + arow) * 1024 + acol8;

    float4 ar[8];   // 4 row-passes x 2 float4 (single buffer, refilled per step)
#pragma unroll
    for (int p = 0; p < 4; ++p) {
        const float* src = abase + (size_t)p * 32 * 1024;
        ar[2 * p]     = *reinterpret_cast<const float4*>(src);
        ar[2 * p + 1] = *reinterpret_cast<const float4*>(src + 4);
    }

    // one k-step: stage A(regs)->LDS, issue B gload_lds, prefetch next A,
    // counted-vmcnt wait, then MFMA.  KMODE: 0 = normal (V), 1 = swapped (K).
    auto step = [&](int k0, bool kmode) {
        __builtin_amdgcn_s_barrier();      // prev MFMA done reading LDS
#pragma unroll
        for (int p = 0; p < 4; ++p)
            *reinterpret_cast<uint4*>(&As[(p * 32 + arow) * 64 + aphys]) =
                pack8(ar[2 * p], ar[2 * p + 1]);
#pragma unroll
        for (int p = 0; p < 4; ++p) {
            const int base = w * 512 + p * 2048;
            const int row  = (base >> 6) + lrow;
            gload16(Bt + (size_t)(col0 + row) * 1024 + k0 + lcol, &Bs[base]);
        }
        __builtin_amdgcn_sched_barrier(0);   // pin: all B issued before A
        if (k0 + 64 < 1024) {
#pragma unroll
            for (int p = 0; p < 4; ++p) {
                const float* src = abase + (size_t)p * 32 * 1024 + (k0 + 64);
                ar[2 * p]     = *reinterpret_cast<const float4*>(src);
                ar[2 * p + 1] = *reinterpret_cast<const float4*>(src + 4);
            }
            __builtin_amdgcn_sched_barrier(0);
            asm volatile("s_waitcnt vmcnt(8)" ::: "memory");   // B landed, A flying
        } else {
            asm volatile("s_waitcnt vmcnt(0)" ::: "memory");
        }
        asm volatile("s_waitcnt lgkmcnt(0)" ::: "memory");     // A ds_writes visible
        __builtin_amdgcn_sched_barrier(0);
        __builtin_amdgcn_s_barrier();
#pragma unroll
        for (int kk = 0; kk < 2; ++kk) {
            bf16x8 af[4], bfr[4];
            const int G = ((kk * 4 + (lane >> 4)) ^ x7) * 8;
#pragma unroll
            for (int m = 0; m < 4; ++m)
                af[m] = *reinterpret_cast<const bf16x8*>(
                    &As[(MROW + m * 16 + (lane & 15)) * 64 + G]);
#pragma unroll
            for (int n = 0; n < 4; ++n)
                bfr[n] = *reinterpret_cast<const bf16x8*>(
                    &Bs[(wc * 64 + n * 16 + (lane & 15)) * 64 + G]);
            if (kmode) {
#pragma unroll
                for (int m = 0; m < 4; ++m)
#pragma unroll
                    for (int n = 0; n < 4; ++n)
                        acc[m][n] = __builtin_amdgcn_mfma_f32_16x16x32_bf16(
                            bfr[n], af[m], acc[m][n], 0, 0, 0);
            } else {
#pragma unroll
                for (int m = 0; m < 4; ++m)
#pragma unroll
                    for (int n = 0; n < 4; ++n)
                        acc[m][n] = __builtin_amdgcn_mfma_f32_16x16x32_bf16(
                            af[m], bfr[n], acc[m][n], 0, 0, 0);
            }
        }
    };

    if (col0 < 1024) {
        for (int k0 = 0; k0 < 1024; k0 += 64) step(k0, true);
        // K epilogue: thread owns 4 consecutive d (reg dim), one k (lane&15)
#pragma unroll
        for (int m = 0; m < 4; ++m) {
            const int gr  = row0 + MROW + m * 16 + (lane & 15);
            const int b   = gr >> 12;
            const int k   = gr & 4095;
            const int kt_i = k >> 6, k_in = k & 63;
#pragma unroll
            for (int n = 0; n < 4; ++n) {
                const int gc0 = col0 + wc * 64 + n * 16 + (lane >> 4) * 4;
                const int h   = gc0 >> 6, d0 = gc0 & 63;
                u16* blob = KT + (((size_t)((b << 4) + h) * 64 + kt_i) << 9) * 8;
                const int og = k_in * 8 + ((d0 >> 3) ^ (k_in & 7));
                ushort4 pk;
                pk.x = f2bf(acc[m][n][0]); pk.y = f2bf(acc[m][n][1]);
                pk.z = f2bf(acc[m][n][2]); pk.w = f2bf(acc[m][n][3]);
                *reinterpret_cast<ushort4*>(&blob[og * 8 + (d0 & 7)]) = pk;
            }
        }
    } else {
        for (int k0 = 0; k0 < 1024; k0 += 64) step(k0, false);
        // V epilogue: thread owns 4 consecutive k (reg dim), one d (lane&15)
#pragma unroll
        for (int m = 0; m < 4; ++m) {
            const int gr0 = row0 + MROW + m * 16 + (lane >> 4) * 4;
            const int b   = gr0 >> 12;
            const int k   = gr0 & 4095;
            const int kt_i = k >> 6, k_in = k & 63;
#pragma unroll
            for (int n = 0; n < 4; ++n) {
                const int gc = col0 + wc * 64 + n * 16 + (lane & 15);
                const int h  = (gc & 1023) >> 6, d = gc & 63;
                u16* blob = VT + (((size_t)((b << 4) + h) * 64 + kt_i) << 9) * 8;
                const int og = d * 8 + ((k_in >> 3) ^ (d & 7));
                ushort4 pk;
                pk.x = f2bf(acc[m][n][0]); pk.y = f2bf(acc[m][n][1]);
                pk.z = f2bf(acc[m][n][2]); pk.w = f2bf(acc[m][n][3]);
                *reinterpret_cast<ushort4*>(&blob[og * 8 + (k_in & 7)]) = pk;
            }
        }
    }
}

// ---------------------------------------------------------------------------
// Split-K bf16 MFMA flash attention, v9: 128-KEY MACRO-TILES (two 64-key
// sub-tiles share one barrier-pair, one max-reduce, one defer-branch, one
// lgkm P-wait).  64 q/block (16 q/wave), double-buffered gload_lds staging
// with counted vmcnt(8).  LDS 80 KB -> 2 blocks/CU.
// Grid: KSPLIT * B * NH * (QL/64) = 1024 blocks, 256 threads.
// ---------------------------------------------------------------------------
__global__ __launch_bounds__(256, 2) void attn_mfma(const u16* __restrict__ Qb,
                                                    const u16* __restrict__ KT,
                                                    const u16* __restrict__ VT2,
                                                    float* __restrict__ Op,
                                                    float* __restrict__ m_ws,
                                                    float* __restrict__ l_ws) {
    __shared__ u16 Ks[2 * 8192];   // [cur][sub][64k x 64d swizzled]
    __shared__ u16 Vs[2 * 8192];   // [cur][sub][64d x 64k swizzled]
    __shared__ u16 Ps[4 * 2048];   // [wave][sub][16q x 64k swizzled]

    const int bid0 = blockIdx.x;
    const int bid  = (bid0 & 7) * 128 + (bid0 >> 3);   // XCD swizzle (1024)
    const int qb   = bid & 15;
    const int h    = (bid >> 4) & 15;
    const int b    = (bid >> 8) & 1;
    const int c    = bid >> 9;
    const int tid  = threadIdx.x;
    const int lane = tid & 63;
    const int w    = tid >> 6;
    const int q_l  = lane & 15;
    const int g    = lane >> 4;
    const int qs7  = q_l & 7;
    const int q0   = qb * 64;
    const int bh   = b * NH + h;

    // Q B-frags (16 q rows per wave)
    bf16x8 qa0, qa1;
    {
        const u16* qsrc = Qb + (size_t)(b * QL + q0 + w * 16 + q_l) * Hh
                          + h * HD + g * 8;
        qa0 = *reinterpret_cast<const bf16x8*>(qsrc);
        qa1 = *reinterpret_cast<const bf16x8*>(qsrc + 32);
    }
    asm volatile("s_waitcnt vmcnt(0)" ::: "memory");

    bf16x8 ones;
#pragma unroll
    for (int e = 0; e < 8; ++e) ones[e] = (short)0x3F80;   // bf16 1.0

    float m_i = -1e30f;
    f32x4 acc_l = (f32x4){0.f, 0.f, 0.f, 0.f};
    f32x4 acc_o[4];
#pragma unroll
    for (int n = 0; n < 4; ++n) acc_o[n] = (f32x4){0.f, 0.f, 0.f, 0.f};

    // hoisted LDS bases
    const int koffA = (g ^ qs7) * 8;
    const int koffB = ((g + 4) ^ qs7) * 8;
    const int rowq  = q_l * 64;
    const u16* kA[2] = { &Ks[rowq + koffA], &Ks[8192 + rowq + koffA] };
    const u16* kB[2] = { &Ks[rowq + koffB], &Ks[8192 + rowq + koffB] };
    const u16* vA[2] = { &Vs[rowq + koffA], &Vs[8192 + rowq + koffA] };
    const u16* vB[2] = { &Vs[rowq + koffB], &Vs[8192 + rowq + koffB] };
    const u16* pA = &Ps[w * 2048 + rowq + koffA];
    const u16* pB = &Ps[w * 2048 + rowq + koffB];
    u16* PsW[4];
#pragma unroll
    for (int n = 0; n < 4; ++n)
        PsW[n] = &Ps[w * 2048 + rowq + (((2 * n + (g >> 1)) ^ qs7) << 3) + (g & 1) * 4];

    // staging pointers (macro-tile = 2 consecutive 4096-u16 blobs)
    const size_t tb0 = ((size_t)bh * 64 + c * (CHUNK / 64)) * 4096;
    const u16* kq = KT  + tb0 + (size_t)(w * 64 + lane) * 8;
    const u16* vq = VT2 + tb0 + (size_t)(w * 64 + lane) * 8;
    u16* kd[2] = { &Ks[w * 512], &Ks[8192 + w * 512] };
    u16* vd[2] = { &Vs[w * 512], &Vs[8192 + w * 512] };

    auto issue8 = [&](const u16* kp, const u16* vp, int bufi) {
        gload16(kp,        kd[bufi]);
        gload16(kp + 2048, kd[bufi] + 2048);
        gload16(kp + 4096, kd[bufi] + 4096);
        gload16(kp + 6144, kd[bufi] + 6144);
        gload16(vp,        vd[bufi]);
        gload16(vp + 2048, vd[bufi] + 2048);
        gload16(vp + 4096, vd[bufi] + 4096);
        gload16(vp + 6144, vd[bufi] + 6144);
    };

    issue8(kq, vq, 0);   // macro-tile 0 -> buf 0

    auto tile = [&](int CUR, int t) {
        const int B0 = CUR * 8192;   // compile-time (CUR literal via unroll)
        __builtin_amdgcn_s_barrier();          // prev compute done with buf CUR^1
        if (t + 1 < NTM) {
            kq += 8192; vq += 8192;
            issue8(kq, vq, CUR ^ 1);
            asm volatile("s_waitcnt vmcnt(8)" ::: "memory");   // buf CUR landed
        } else {
            asm volatile("s_waitcnt vmcnt(0)" ::: "memory");
        }
        __builtin_amdgcn_sched_barrier(0);
        __builtin_amdgcn_s_barrier();          // all waves' buf CUR resident

        // QK^T swapped over 128 keys: s[n][r] = S[key = n*16+g*4+r][q_l]
        f32x4 s[8];
        __builtin_amdgcn_s_setprio(1);
#pragma unroll
        for (int n = 0; n < 8; ++n) {
            bf16x8 a0 = *reinterpret_cast<const bf16x8*>(kA[CUR] + n * 1024);
            bf16x8 a1 = *reinterpret_cast<const bf16x8*>(kB[CUR] + n * 1024);
            f32x4 z = (f32x4){0.f, 0.f, 0.f, 0.f};
            z = __builtin_amdgcn_mfma_f32_16x16x32_bf16(a0, qa0, z, 0, 0, 0);
            z = __builtin_amdgcn_mfma_f32_16x16x32_bf16(a1, qa1, z, 0, 0, 0);
            s[n] = z;
        }
        __builtin_amdgcn_s_setprio(0);

        // ONE max-reduce over all 32 scores (15 max3 + fmax + 2 shfl)
        float mx = max3f(s[0][0], s[0][1], s[0][2]);
#pragma unroll
        for (int i = 3; i + 1 < 32; i += 2)
            mx = max3f(mx, s[i >> 2][i & 3], s[(i + 1) >> 2][(i + 1) & 3]);
        mx = fmaxf(mx, s[7][3]);
        mx = fmaxf(mx, __shfl_xor(mx, 16));
        mx = fmaxf(mx, __shfl_xor(mx, 32));

        if (__any(mx > m_i + RTHR)) {          // defer-max (once per 128 keys)
            const float mnew = fmaxf(m_i, mx);
            const float al   = exp2f(m_i - mnew);
            m_i = mnew;
            acc_l[0] *= al; acc_l[1] *= al; acc_l[2] *= al; acc_l[3] *= al;
#pragma unroll
            for (int n = 0; n < 4; ++n) {
                f32x4 tt = acc_o[n];
                tt[0] *= al; tt[1] *= al; tt[2] *= al; tt[3] *= al;
                acc_o[n] = tt;
            }
        }
#pragma unroll
        for (int n = 0; n < 8; ++n)
#pragma unroll
            for (int r = 0; r < 4; ++r) s[n][r] = exp2f(s[n][r] - m_i);

        // pack P -> bf16 into both sub-tiles (swizzled slots)
#pragma unroll
        for (int n = 0; n < 8; ++n) {
            uint2 pk2;
            pk2.x = cvt_pk_bf16(s[n][0], s[n][1]);
            pk2.y = cvt_pk_bf16(s[n][2], s[n][3]);
            *reinterpret_cast<uint2*>(PsW[n & 3] + (n >> 2) * 1024) = pk2;
        }
        asm volatile("s_waitcnt lgkmcnt(0)" ::: "memory");
        __builtin_amdgcn_sched_barrier(0);

        // PV over 128 keys (4 k-slots) + l via ones-MFMA
        __builtin_amdgcn_s_setprio(1);
#pragma unroll
        for (int kf = 0; kf < 4; ++kf) {
            const int sub = kf >> 1;
            const u16* pr = ((kf & 1) ? pB : pA) + sub * 1024;
            bf16x8 pfr = *reinterpret_cast<const bf16x8*>(pr);
            acc_l = __builtin_amdgcn_mfma_f32_16x16x32_bf16(ones, pfr, acc_l, 0, 0, 0);
            const u16* vb = ((kf & 1) ? vB[CUR] : vA[CUR]) + sub * 4096;
#pragma unroll
            for (int n = 0; n < 4; ++n) {
                bf16x8 vf = *reinterpret_cast<const bf16x8*>(vb + n * 1024);
                acc_o[n] = __builtin_amdgcn_mfma_f32_16x16x32_bf16(
                    vf, pfr, acc_o[n], 0, 0, 0);
            }
        }
        __builtin_amdgcn_s_setprio(0);
    };

    for (int t = 0; t < NTM; t += 2) {
        tile(0, t);
        tile(1, t + 1);
    }

    // epilogue: unnormalized O (float4 stores) + per-row m,l
    float* opc = Op + (size_t)c * ((size_t)Bb * QL * Hh)
                 + (size_t)(b * QL + q0 + w * 16 + q_l) * Hh + h * HD;
#pragma unroll
    for (int n = 0; n < 4; ++n) {
        float4 v = make_float4(acc_o[n][0], acc_o[n][1], acc_o[n][2], acc_o[n][3]);
        *reinterpret_cast<float4*>(opc + n * 16 + g * 4) = v;
    }
    if (g == 0) {
        const int idx = ((c * Bb + b) * NH + h) * QL + q0 + w * 16 + q_l;
        m_ws[idx] = m_i;
        l_ws[idx] = acc_l[0];
    }
}

// ---------------------------------------------------------------------------
// Output GEMM with FUSED split-K combine in A-staging.  BMT=64.
// ---------------------------------------------------------------------------
__global__ __launch_bounds__(256) void ogemm(const float* __restrict__ Op,
                                             const float* __restrict__ m_ws,
                                             const float* __restrict__ l_ws,
                                             const u16* __restrict__ Bt,
                                             float* __restrict__ C) {
    __shared__ u16 As[64 * 64];
    __shared__ u16 Bs[128 * 64];
    const int nwg = gridDim.x * gridDim.y;
    const int id  = blockIdx.y * gridDim.x + blockIdx.x;
    const int sw  = (id & 7) * (nwg >> 3) + (id >> 3);
    const int bx  = sw % gridDim.x, by = sw / gridDim.x;
    const int tid = threadIdx.x, lane = tid & 63, w = tid >> 6;
    const int wr = w >> 1, wc = w & 1;
    const int row0 = by * 64, col0 = bx * 128;
    const int MROW = wr * 32;
    const int x7   = lane & 7;

    f32x4 acc[2][4];
#pragma unroll
    for (int m = 0; m < 2; ++m)
#pragma unroll
        for (int n = 0; n < 4; ++n) acc[m][n] = (f32x4){0.f, 0.f, 0.f, 0.f};

    const int lrow = lane >> 3, lcol = (lane & 7) * 8;
    const int arow = tid >> 3, acol8 = (tid & 7) * 8;
    const int aphys = acol8 ^ ((arow & 7) << 3);

    for (int k0 = 0; k0 < 1024; k0 += 64) {
        __syncthreads();
        const int h_ = k0 >> 6;   // uniform per step
#pragma unroll
        for (int p = 0; p < 2; ++p) {
            const int r    = p * 32 + arow;
            const int grow = row0 + r;
            const int b_   = grow >> 10, q_ = grow & 1023;
            const int idx  = (((b_ << 4) + h_) << 10) + q_;
            const float m0 = m_ws[idx], m1 = m_ws[idx + 32768];
            const float l0 = l_ws[idx], l1 = l_ws[idx + 32768];
            const float ms = fmaxf(m0, m1);
            float a0 = exp2f(m0 - ms), a1 = exp2f(m1 - ms);
            const float inv = 1.f / (l0 * a0 + l1 * a1);
            a0 *= inv; a1 *= inv;
            const float* o0 = Op + (size_t)grow * 1024 + k0 + acol8;
            const float* o1 = o0 + (size_t)Bb * QL * Hh;
            float4 x0 = *reinterpret_cast<const float4*>(o0);
            float4 x1 = *reinterpret_cast<const float4*>(o0 + 4);
            float4 y0 = *reinterpret_cast<const float4*>(o1);
            float4 y1 = *reinterpret_cast<const float4*>(o1 + 4);
            float4 f0 = make_float4(x0.x * a0 + y0.x * a1, x0.y * a0 + y0.y * a1,
                                    x0.z * a0 + y0.z * a1, x0.w * a0 + y0.w * a1);
            float4 f1 = make_float4(x1.x * a0 + y1.x * a1, x1.y * a0 + y1.y * a1,
                                    x1.z * a0 + y1.z * a1, x1.w * a0 + y1.w * a1);
            *reinterpret_cast<uint4*>(&As[r * 64 + aphys]) = pack8(f0, f1);
        }
#pragma unroll
        for (int p = 0; p < 4; ++p) {
            const int base = w * 512 + p * 2048;
            const int row  = (base >> 6) + lrow;
            gload16(Bt + (size_t)(col0 + row) * 1024 + k0 + lcol, &Bs[base]);
        }
        __syncthreads();
#pragma unroll
        for (int kk = 0; kk < 2; ++kk) {
            bf16x8 af[2], bfr[4];
            const int G = ((kk * 4 + (lane >> 4)) ^ x7) * 8;
#pragma unroll
            for (int m = 0; m < 2; ++m)
                af[m] = *reinterpret_cast<const bf16x8*>(
                    &As[(MROW + m * 16 + (lane & 15)) * 64 + G]);
#pragma unroll
            for (int n = 0; n < 4; ++n)
                bfr[n] = *reinterpret_cast<const bf16x8*>(
                    &Bs[(wc * 64 + n * 16 + (lane & 15)) * 64 + G]);
#pragma unroll
            for (int m = 0; m < 2; ++m)
#pragma unroll
                for (int n = 0; n < 4; ++n)
                    acc[m][n] = __builtin_amdgcn_mfma_f32_16x16x32_bf16(
                        af[m], bfr[n], acc[m][n], 0, 0, 0);
        }
    }
#pragma unroll
    for (int m = 0; m < 2; ++m)
#pragma unroll
        for (int n = 0; n < 4; ++n) {
            const int gc = col0 + wc * 64 + n * 16 + (lane & 15);
#pragma unroll
            for (int r = 0; r < 4; ++r) {
                const int gr = row0 + MROW + m * 16 + (lane >> 4) * 4 + r;
                C[(size_t)gr * 1024 + gc] = acc[m][n][r];
            }
        }
}

// ---------------------------------------------------------------------------
// Launch.  Workspace:
//   0-16 KT | 16-32 VT | 32-48 Opart | 48-52 Qb | 52-56 wkvT
//  56-58 wqT | 58-60 woutT | 60-60.25 m_ws | 60.25-60.5 l_ws
// ---------------------------------------------------------------------------
extern "C" void kernel_launch(void* const* d_in, const int* in_sizes, int n_in,
                              void* d_out, int out_size, void* d_ws, size_t ws_size,
                              hipStream_t stream) {
    const float* query     = (const float*)d_in[0];
    const float* key_value = (const float*)d_in[1];
    const float* w_q       = (const float*)d_in[2];
    const float* w_kv      = (const float*)d_in[3];
    const float* w_out     = (const float*)d_in[4];
    float* out = (float*)d_out;

    char* ws = (char*)d_ws;
    const size_t MB = 1024 * 1024;
    u16*   KT    = (u16*)(ws);
    u16*   VT    = (u16*)(ws + 16 * MB);
    float* Opart = (float*)(ws + 32 * MB);
    u16*   Qb    = (u16*)(ws + 48 * MB);
    u16*   wkvT  = (u16*)(ws + 52 * MB);
    u16*   wqT   = (u16*)(ws + 56 * MB);
    u16*   woutT = (u16*)(ws + 58 * MB);
    float* m_wsp = (float*)(ws + 60 * MB);
    float* l_wsp = (float*)(ws + 60 * MB + 256 * 1024);

    dim3 blk(256);

    // 1) all weight transposes (swizzled layout) in one launch
    wtrans_all<<<1024, blk, 0, stream>>>(w_q, w_kv, w_out, wqT, wkvT, woutT);

    // 2) Q projection (fused fp32 cast; log2-domain scale)
    qgemm<<<dim3(8, 32), blk, 0, stream>>>(query, wqT, Qb);

    // 3) KV projection (A-reg pipelined; fused swizzled blob epilogues)
    kvgemm<<<dim3(16, 64), blk, 0, stream>>>(key_value, wkvT, KT, VT);

    // 4) split-K flash attention (128-key macro-tiles, 1024 blocks)
    attn_mfma<<<dim3(KSPLIT * 512), blk, 0, stream>>>(
        Qb, KT, VT, Opart, m_wsp, l_wsp);

    // 5) output GEMM (fused split-K combine in A-staging)
    ogemm<<<dim3(8, 32), blk, 0, stream>>>(Opart, m_wsp, l_wsp, woutT, out);
}

// Round 10
// 192.046 us; speedup vs baseline: 1.2409x; 1.2409x over previous
//
#include <hip/hip_runtime.h>

// Problem constants (CompactCrossAttention)
#define Bb   2
#define QL   1024
#define KL   4096
#define Hh   1024
#define NH   16
#define HD   64

#define KSPLIT 2
#define CHUNK  (KL / KSPLIT)   // 2048 keys per block
#define NTM    (CHUNK / 128)   // 16 macro-tiles of 128 keys

typedef unsigned short u16;
typedef __attribute__((ext_vector_type(8))) short bf16x8;   // MFMA A/B frag
typedef __attribute__((ext_vector_type(8))) unsigned short usv8;
typedef __attribute__((ext_vector_type(4))) float f32x4;    // MFMA C/D frag

#define QSCALE 0.1803368801111204f   // 0.125 * log2(e): scores in log2 domain
#define RTHR   11.0f                 // defer-max threshold (log2 units)

__device__ __forceinline__ u16 f2bf(float f) {
    union { float f; unsigned int u; } v; v.f = f;
    unsigned int r = (v.u + 0x7FFFu + ((v.u >> 16) & 1u)) >> 16;
    return (u16)r;
}

__device__ __forceinline__ unsigned int cvt_pk_bf16(float lo, float hi) {
    unsigned int r;
    asm("v_cvt_pk_bf16_f32 %0, %1, %2" : "=v"(r) : "v"(lo), "v"(hi));
    return r;
}

__device__ __forceinline__ float max3f(float a, float b, float c) {
    float r;
    asm("v_max3_f32 %0, %1, %2, %3" : "=v"(r) : "v"(a), "v"(b), "v"(c));
    return r;
}

__device__ __forceinline__ void gload16(const void* g, void* l) {
    __builtin_amdgcn_global_load_lds(
        (const __attribute__((address_space(1))) void*)g,
        (__attribute__((address_space(3))) void*)l, 16, 0, 0);
}

// pack 8 fp32 -> 8 bf16 (uint4)
__device__ __forceinline__ uint4 pack8(const float4& f0, const float4& f1) {
    uint4 o;
    o.x = cvt_pk_bf16(f0.x, f0.y);
    o.y = cvt_pk_bf16(f0.z, f0.w);
    o.z = cvt_pk_bf16(f1.x, f1.y);
    o.w = cvt_pk_bf16(f1.z, f1.w);
    return o;
}

// ---------------------------------------------------------------------------
// All three weight transposes (fp32 [R][C] -> bf16 [C][R]) in ONE launch.
// Output rows GRANULE-SWIZZLED: logical k-granule gl at slot gl ^ (n&7).
// ---------------------------------------------------------------------------
__global__ __launch_bounds__(256) void wtrans_all(const float* __restrict__ wq,
                                                  const float* __restrict__ wkv,
                                                  const float* __restrict__ wout,
                                                  u16* __restrict__ wqT,
                                                  u16* __restrict__ wkvT,
                                                  u16* __restrict__ woutT) {
    __shared__ float T[64][65];
    int bid = blockIdx.x;
    const float* in; u16* out; int C;
    if (bid < 256)      { in = wq;   out = wqT;   C = 1024; }
    else if (bid < 768) { in = wkv;  out = wkvT;  C = 2048; bid -= 256; }
    else                { in = wout; out = woutT; C = 1024; bid -= 768; }
    const int nc = C >> 6;
    const int c0 = (bid % nc) * 64;
    const int r0 = (bid / nc) * 64;
    const int t  = threadIdx.x;
    const int tx = t & 15, ty = t >> 4;
#pragma unroll
    for (int p = 0; p < 4; ++p) {
        const int r = ty + p * 16;
        float4 v = *reinterpret_cast<const float4*>(in + (size_t)(r0 + r) * C + c0 + tx * 4);
        T[r][tx * 4 + 0] = v.x; T[r][tx * 4 + 1] = v.y;
        T[r][tx * 4 + 2] = v.z; T[r][tx * 4 + 3] = v.w;
    }
    __syncthreads();
#pragma unroll
    for (int p = 0; p < 4; ++p) {
        const int c = ty + p * 16;
        const int n = c0 + c;
        ushort4 o;
        o.x = f2bf(T[tx * 4 + 0][c]); o.y = f2bf(T[tx * 4 + 1][c]);
        o.z = f2bf(T[tx * 4 + 2][c]); o.w = f2bf(T[tx * 4 + 3][c]);
        const int kb   = r0 + tx * 4;
        const int kout = (kb & ~63) | ((((kb >> 3) & 7) ^ (n & 7)) << 3) | (kb & 7);
        *reinterpret_cast<ushort4*>(out + (size_t)n * 1024 + kout) = o;
    }
}

// ---------------------------------------------------------------------------
// Q projection GEMM: Qb = QSCALE * (query_f32 @ wqT^T).  BMT=64.
// ---------------------------------------------------------------------------
__global__ __launch_bounds__(256) void qgemm(const float* __restrict__ A32,
                                             const u16* __restrict__ Bt,
                                             u16* __restrict__ C) {
    __shared__ u16 As[64 * 64];
    __shared__ u16 Bs[128 * 64];
    const int nwg = gridDim.x * gridDim.y;
    const int id  = blockIdx.y * gridDim.x + blockIdx.x;
    const int sw  = (id & 7) * (nwg >> 3) + (id >> 3);   // chunked per-XCD
    const int bx  = sw % gridDim.x, by = sw / gridDim.x;
    const int tid = threadIdx.x, lane = tid & 63, w = tid >> 6;
    const int wr = w >> 1, wc = w & 1;
    const int row0 = by * 64, col0 = bx * 128;
    const int MROW = wr * 32;
    const int x7   = lane & 7;

    f32x4 acc[2][4];
#pragma unroll
    for (int m = 0; m < 2; ++m)
#pragma unroll
        for (int n = 0; n < 4; ++n) acc[m][n] = (f32x4){0.f, 0.f, 0.f, 0.f};

    const int lrow = lane >> 3, lcol = (lane & 7) * 8;
    const int arow = tid >> 3, acol8 = (tid & 7) * 8;
    const int aphys = acol8 ^ ((arow & 7) << 3);

    for (int k0 = 0; k0 < 1024; k0 += 64) {
        __syncthreads();
#pragma unroll
        for (int p = 0; p < 2; ++p) {
            const int r = p * 32 + arow;
            const float* src = A32 + (size_t)(row0 + r) * 1024 + k0 + acol8;
            float4 f0 = *reinterpret_cast<const float4*>(src);
            float4 f1 = *reinterpret_cast<const float4*>(src + 4);
            *reinterpret_cast<uint4*>(&As[r * 64 + aphys]) = pack8(f0, f1);
        }
#pragma unroll
        for (int p = 0; p < 4; ++p) {
            const int base = w * 512 + p * 2048;
            const int row  = (base >> 6) + lrow;
            gload16(Bt + (size_t)(col0 + row) * 1024 + k0 + lcol, &Bs[base]);
        }
        __syncthreads();
#pragma unroll
        for (int kk = 0; kk < 2; ++kk) {
            bf16x8 af[2], bfr[4];
            const int G = ((kk * 4 + (lane >> 4)) ^ x7) * 8;
#pragma unroll
            for (int m = 0; m < 2; ++m)
                af[m] = *reinterpret_cast<const bf16x8*>(
                    &As[(MROW + m * 16 + (lane & 15)) * 64 + G]);
#pragma unroll
            for (int n = 0; n < 4; ++n)
                bfr[n] = *reinterpret_cast<const bf16x8*>(
                    &Bs[(wc * 64 + n * 16 + (lane & 15)) * 64 + G]);
#pragma unroll
            for (int m = 0; m < 2; ++m)
#pragma unroll
                for (int n = 0; n < 4; ++n)
                    acc[m][n] = __builtin_amdgcn_mfma_f32_16x16x32_bf16(
                        af[m], bfr[n], acc[m][n], 0, 0, 0);
        }
    }
#pragma unroll
    for (int m = 0; m < 2; ++m)
#pragma unroll
        for (int n = 0; n < 4; ++n) {
            const int gc = col0 + wc * 64 + n * 16 + (lane & 15);
#pragma unroll
            for (int r = 0; r < 4; ++r) {
                const int gr = row0 + MROW + m * 16 + (lane >> 4) * 4 + r;
                C[(size_t)gr * 1024 + gc] = f2bf(acc[m][n][r] * QSCALE);
            }
        }
}

// ---------------------------------------------------------------------------
// KV projection GEMM -> pre-swizzled K/V blobs (round-8 proven version:
// plain __syncthreads staging, no reg pipeline, VGPR ~92).
// ---------------------------------------------------------------------------
__global__ __launch_bounds__(256) void kvgemm(const float* __restrict__ A32,
                                              const u16* __restrict__ Bt,
                                              u16* __restrict__ KT,
                                              u16* __restrict__ VT) {
    __shared__ u16 As[128 * 64];
    __shared__ u16 Bs[128 * 64];
    const int nwg = gridDim.x * gridDim.y;
    const int id  = blockIdx.y * gridDim.x + blockIdx.x;
    const int sw  = (id & 7) * (nwg >> 3) + (id >> 3);
    const int bx  = sw % gridDim.x, by = sw / gridDim.x;
    const int tid = threadIdx.x, lane = tid & 63, w = tid >> 6;
    const int wr = w >> 1, wc = w & 1;
    const int row0 = by * 128, col0 = bx * 128;
    const int MROW = wr * 64;
    const int x7   = lane & 7;

    f32x4 acc[4][4];
#pragma unroll
    for (int m = 0; m < 4; ++m)
#pragma unroll
        for (int n = 0; n < 4; ++n) acc[m][n] = (f32x4){0.f, 0.f, 0.f, 0.f};

    const int lrow = lane >> 3, lcol = (lane & 7) * 8;
    const int arow = tid >> 3, acol8 = (tid & 7) * 8;
    const int aphys = acol8 ^ ((arow & 7) << 3);

    auto stage = [&](int k0) {
        __syncthreads();
#pragma unroll
        for (int p = 0; p < 4; ++p) {
            const int r = p * 32 + arow;
            const float* src = A32 + (size_t)(row0 + r) * 1024 + k0 + acol8;
            float4 f0 = *reinterpret_cast<const float4*>(src);
            float4 f1 = *reinterpret_cast<const float4*>(src + 4);
            *reinterpret_cast<uint4*>(&As[r * 64 + aphys]) = pack8(f0, f1);
        }
#pragma unroll
        for (int p = 0; p < 4; ++p) {
            const int base = w * 512 + p * 2048;
            const int row  = (base >> 6) + lrow;
            gload16(Bt + (size_t)(col0 + row) * 1024 + k0 + lcol, &Bs[base]);
        }
        __syncthreads();
    };

    if (col0 < 1024) {
        // K orientation: acc = mfma(bfr, af) -> thread owns 4 consecutive d
        for (int k0 = 0; k0 < 1024; k0 += 64) {
            stage(k0);
#pragma unroll
            for (int kk = 0; kk < 2; ++kk) {
                bf16x8 af[4], bfr[4];
                const int G = ((kk * 4 + (lane >> 4)) ^ x7) * 8;
#pragma unroll
                for (int m = 0; m < 4; ++m)
                    af[m] = *reinterpret_cast<const bf16x8*>(
                        &As[(MROW + m * 16 + (lane & 15)) * 64 + G]);
#pragma unroll
                for (int n = 0; n < 4; ++n)
                    bfr[n] = *reinterpret_cast<const bf16x8*>(
                        &Bs[(wc * 64 + n * 16 + (lane & 15)) * 64 + G]);
#pragma unroll
                for (int m = 0; m < 4; ++m)
#pragma unroll
                    for (int n = 0; n < 4; ++n)
                        acc[m][n] = __builtin_amdgcn_mfma_f32_16x16x32_bf16(
                            bfr[n], af[m], acc[m][n], 0, 0, 0);
            }
        }
#pragma unroll
        for (int m = 0; m < 4; ++m) {
            const int gr  = row0 + MROW + m * 16 + (lane & 15);
            const int b   = gr >> 12;
            const int k   = gr & 4095;
            const int kt_i = k >> 6, k_in = k & 63;
#pragma unroll
            for (int n = 0; n < 4; ++n) {
                const int gc0 = col0 + wc * 64 + n * 16 + (lane >> 4) * 4;
                const int h   = gc0 >> 6, d0 = gc0 & 63;
                u16* blob = KT + (((size_t)((b << 4) + h) * 64 + kt_i) << 9) * 8;
                const int og = k_in * 8 + ((d0 >> 3) ^ (k_in & 7));
                ushort4 pk;
                pk.x = f2bf(acc[m][n][0]); pk.y = f2bf(acc[m][n][1]);
                pk.z = f2bf(acc[m][n][2]); pk.w = f2bf(acc[m][n][3]);
                *reinterpret_cast<ushort4*>(&blob[og * 8 + (d0 & 7)]) = pk;
            }
        }
    } else {
        // V orientation: normal mfma(af, bfr) -> thread owns 4 consecutive k
        for (int k0 = 0; k0 < 1024; k0 += 64) {
            stage(k0);
#pragma unroll
            for (int kk = 0; kk < 2; ++kk) {
                bf16x8 af[4], bfr[4];
                const int G = ((kk * 4 + (lane >> 4)) ^ x7) * 8;
#pragma unroll
                for (int m = 0; m < 4; ++m)
                    af[m] = *reinterpret_cast<const bf16x8*>(
                        &As[(MROW + m * 16 + (lane & 15)) * 64 + G]);
#pragma unroll
                for (int n = 0; n < 4; ++n)
                    bfr[n] = *reinterpret_cast<const bf16x8*>(
                        &Bs[(wc * 64 + n * 16 + (lane & 15)) * 64 + G]);
#pragma unroll
                for (int m = 0; m < 4; ++m)
#pragma unroll
                    for (int n = 0; n < 4; ++n)
                        acc[m][n] = __builtin_amdgcn_mfma_f32_16x16x32_bf16(
                            af[m], bfr[n], acc[m][n], 0, 0, 0);
            }
        }
#pragma unroll
        for (int m = 0; m < 4; ++m) {
            const int gr0 = row0 + MROW + m * 16 + (lane >> 4) * 4;
            const int b   = gr0 >> 12;
            const int k   = gr0 & 4095;
            const int kt_i = k >> 6, k_in = k & 63;
#pragma unroll
            for (int n = 0; n < 4; ++n) {
                const int gc = col0 + wc * 64 + n * 16 + (lane & 15);
                const int h  = (gc & 1023) >> 6, d = gc & 63;
                u16* blob = VT + (((size_t)((b << 4) + h) * 64 + kt_i) << 9) * 8;
                const int og = d * 8 + ((k_in >> 3) ^ (d & 7));
                ushort4 pk;
                pk.x = f2bf(acc[m][n][0]); pk.y = f2bf(acc[m][n][1]);
                pk.z = f2bf(acc[m][n][2]); pk.w = f2bf(acc[m][n][3]);
                *reinterpret_cast<ushort4*>(&blob[og * 8 + (k_in & 7)]) = pk;
            }
        }
    }
}

// ---------------------------------------------------------------------------
// Split-K bf16 MFMA flash attention, v9 (kept): 128-KEY MACRO-TILES.
// 64 q/block (16 q/wave), double-buffered gload_lds, counted vmcnt(8).
// Grid: KSPLIT * B * NH * (QL/64) = 1024 blocks, 256 threads.
// ---------------------------------------------------------------------------
__global__ __launch_bounds__(256, 2) void attn_mfma(const u16* __restrict__ Qb,
                                                    const u16* __restrict__ KT,
                                                    const u16* __restrict__ VT2,
                                                    float* __restrict__ Op,
                                                    float* __restrict__ m_ws,
                                                    float* __restrict__ l_ws) {
    __shared__ u16 Ks[2 * 8192];   // [cur][sub][64k x 64d swizzled]
    __shared__ u16 Vs[2 * 8192];   // [cur][sub][64d x 64k swizzled]
    __shared__ u16 Ps[4 * 2048];   // [wave][sub][16q x 64k swizzled]

    const int bid0 = blockIdx.x;
    const int bid  = (bid0 & 7) * 128 + (bid0 >> 3);   // XCD swizzle (1024)
    const int qb   = bid & 15;
    const int h    = (bid >> 4) & 15;
    const int b    = (bid >> 8) & 1;
    const int c    = bid >> 9;
    const int tid  = threadIdx.x;
    const int lane = tid & 63;
    const int w    = tid >> 6;
    const int q_l  = lane & 15;
    const int g    = lane >> 4;
    const int qs7  = q_l & 7;
    const int q0   = qb * 64;
    const int bh   = b * NH + h;

    // Q B-frags (16 q rows per wave)
    bf16x8 qa0, qa1;
    {
        const u16* qsrc = Qb + (size_t)(b * QL + q0 + w * 16 + q_l) * Hh
                          + h * HD + g * 8;
        qa0 = *reinterpret_cast<const bf16x8*>(qsrc);
        qa1 = *reinterpret_cast<const bf16x8*>(qsrc + 32);
    }
    asm volatile("s_waitcnt vmcnt(0)" ::: "memory");

    bf16x8 ones;
#pragma unroll
    for (int e = 0; e < 8; ++e) ones[e] = (short)0x3F80;   // bf16 1.0

    float m_i = -1e30f;
    f32x4 acc_l = (f32x4){0.f, 0.f, 0.f, 0.f};
    f32x4 acc_o[4];
#pragma unroll
    for (int n = 0; n < 4; ++n) acc_o[n] = (f32x4){0.f, 0.f, 0.f, 0.f};

    // hoisted LDS bases
    const int koffA = (g ^ qs7) * 8;
    const int koffB = ((g + 4) ^ qs7) * 8;
    const int rowq  = q_l * 64;
    const u16* kA[2] = { &Ks[rowq + koffA], &Ks[8192 + rowq + koffA] };
    const u16* kB[2] = { &Ks[rowq + koffB], &Ks[8192 + rowq + koffB] };
    const u16* vA[2] = { &Vs[rowq + koffA], &Vs[8192 + rowq + koffA] };
    const u16* vB[2] = { &Vs[rowq + koffB], &Vs[8192 + rowq + koffB] };
    const u16* pA = &Ps[w * 2048 + rowq + koffA];
    const u16* pB = &Ps[w * 2048 + rowq + koffB];
    u16* PsW[4];
#pragma unroll
    for (int n = 0; n < 4; ++n)
        PsW[n] = &Ps[w * 2048 + rowq + (((2 * n + (g >> 1)) ^ qs7) << 3) + (g & 1) * 4];

    // staging pointers (macro-tile = 2 consecutive 4096-u16 blobs)
    const size_t tb0 = ((size_t)bh * 64 + c * (CHUNK / 64)) * 4096;
    const u16* kq = KT  + tb0 + (size_t)(w * 64 + lane) * 8;
    const u16* vq = VT2 + tb0 + (size_t)(w * 64 + lane) * 8;
    u16* kd[2] = { &Ks[w * 512], &Ks[8192 + w * 512] };
    u16* vd[2] = { &Vs[w * 512], &Vs[8192 + w * 512] };

    auto issue8 = [&](const u16* kp, const u16* vp, int bufi) {
        gload16(kp,        kd[bufi]);
        gload16(kp + 2048, kd[bufi] + 2048);
        gload16(kp + 4096, kd[bufi] + 4096);
        gload16(kp + 6144, kd[bufi] + 6144);
        gload16(vp,        vd[bufi]);
        gload16(vp + 2048, vd[bufi] + 2048);
        gload16(vp + 4096, vd[bufi] + 4096);
        gload16(vp + 6144, vd[bufi] + 6144);
    };

    issue8(kq, vq, 0);   // macro-tile 0 -> buf 0

    auto tile = [&](int CUR, int t) {
        __builtin_amdgcn_s_barrier();          // prev compute done with buf CUR^1
        if (t + 1 < NTM) {
            kq += 8192; vq += 8192;
            issue8(kq, vq, CUR ^ 1);
            asm volatile("s_waitcnt vmcnt(8)" ::: "memory");   // buf CUR landed
        } else {
            asm volatile("s_waitcnt vmcnt(0)" ::: "memory");
        }
        __builtin_amdgcn_sched_barrier(0);
        __builtin_amdgcn_s_barrier();          // all waves' buf CUR resident

        // QK^T swapped over 128 keys: s[n][r] = S[key = n*16+g*4+r][q_l]
        f32x4 s[8];
        __builtin_amdgcn_s_setprio(1);
#pragma unroll
        for (int n = 0; n < 8; ++n) {
            bf16x8 a0 = *reinterpret_cast<const bf16x8*>(kA[CUR] + n * 1024);
            bf16x8 a1 = *reinterpret_cast<const bf16x8*>(kB[CUR] + n * 1024);
            f32x4 z = (f32x4){0.f, 0.f, 0.f, 0.f};
            z = __builtin_amdgcn_mfma_f32_16x16x32_bf16(a0, qa0, z, 0, 0, 0);
            z = __builtin_amdgcn_mfma_f32_16x16x32_bf16(a1, qa1, z, 0, 0, 0);
            s[n] = z;
        }
        __builtin_amdgcn_s_setprio(0);

        // ONE max-reduce over all 32 scores (15 max3 + fmax + 2 shfl)
        float mx = max3f(s[0][0], s[0][1], s[0][2]);
#pragma unroll
        for (int i = 3; i + 1 < 32; i += 2)
            mx = max3f(mx, s[i >> 2][i & 3], s[(i + 1) >> 2][(i + 1) & 3]);
        mx = fmaxf(mx, s[7][3]);
        mx = fmaxf(mx, __shfl_xor(mx, 16));
        mx = fmaxf(mx, __shfl_xor(mx, 32));

        if (__any(mx > m_i + RTHR)) {          // defer-max (once per 128 keys)
            const float mnew = fmaxf(m_i, mx);
            const float al   = exp2f(m_i - mnew);
            m_i = mnew;
            acc_l[0] *= al; acc_l[1] *= al; acc_l[2] *= al; acc_l[3] *= al;
#pragma unroll
            for (int n = 0; n < 4; ++n) {
                f32x4 tt = acc_o[n];
                tt[0] *= al; tt[1] *= al; tt[2] *= al; tt[3] *= al;
                acc_o[n] = tt;
            }
        }
#pragma unroll
        for (int n = 0; n < 8; ++n)
#pragma unroll
            for (int r = 0; r < 4; ++r) s[n][r] = exp2f(s[n][r] - m_i);

        // pack P -> bf16 into both sub-tiles (swizzled slots)
#pragma unroll
        for (int n = 0; n < 8; ++n) {
            uint2 pk2;
            pk2.x = cvt_pk_bf16(s[n][0], s[n][1]);
            pk2.y = cvt_pk_bf16(s[n][2], s[n][3]);
            *reinterpret_cast<uint2*>(PsW[n & 3] + (n >> 2) * 1024) = pk2;
        }
        asm volatile("s_waitcnt lgkmcnt(0)" ::: "memory");
        __builtin_amdgcn_sched_barrier(0);

        // PV over 128 keys (4 k-slots) + l via ones-MFMA
        __builtin_amdgcn_s_setprio(1);
#pragma unroll
        for (int kf = 0; kf < 4; ++kf) {
            const int sub = kf >> 1;
            const u16* pr = ((kf & 1) ? pB : pA) + sub * 1024;
            bf16x8 pfr = *reinterpret_cast<const bf16x8*>(pr);
            acc_l = __builtin_amdgcn_mfma_f32_16x16x32_bf16(ones, pfr, acc_l, 0, 0, 0);
            const u16* vb = ((kf & 1) ? vB[CUR] : vA[CUR]) + sub * 4096;
#pragma unroll
            for (int n = 0; n < 4; ++n) {
                bf16x8 vf = *reinterpret_cast<const bf16x8*>(vb + n * 1024);
                acc_o[n] = __builtin_amdgcn_mfma_f32_16x16x32_bf16(
                    vf, pfr, acc_o[n], 0, 0, 0);
            }
        }
        __builtin_amdgcn_s_setprio(0);
    };

    for (int t = 0; t < NTM; t += 2) {
        tile(0, t);
        tile(1, t + 1);
    }

    // epilogue: unnormalized O (float4 stores) + per-row m,l
    float* opc = Op + (size_t)c * ((size_t)Bb * QL * Hh)
                 + (size_t)(b * QL + q0 + w * 16 + q_l) * Hh + h * HD;
#pragma unroll
    for (int n = 0; n < 4; ++n) {
        float4 v = make_float4(acc_o[n][0], acc_o[n][1], acc_o[n][2], acc_o[n][3]);
        *reinterpret_cast<float4*>(opc + n * 16 + g * 4) = v;
    }
    if (g == 0) {
        const int idx = ((c * Bb + b) * NH + h) * QL + q0 + w * 16 + q_l;
        m_ws[idx] = m_i;
        l_ws[idx] = acc_l[0];
    }
}

// ---------------------------------------------------------------------------
// Output GEMM with FUSED split-K combine in A-staging.  BMT=64.
// ---------------------------------------------------------------------------
__global__ __launch_bounds__(256) void ogemm(const float* __restrict__ Op,
                                             const float* __restrict__ m_ws,
                                             const float* __restrict__ l_ws,
                                             const u16* __restrict__ Bt,
                                             float* __restrict__ C) {
    __shared__ u16 As[64 * 64];
    __shared__ u16 Bs[128 * 64];
    const int nwg = gridDim.x * gridDim.y;
    const int id  = blockIdx.y * gridDim.x + blockIdx.x;
    const int sw  = (id & 7) * (nwg >> 3) + (id >> 3);
    const int bx  = sw % gridDim.x, by = sw / gridDim.x;
    const int tid = threadIdx.x, lane = tid & 63, w = tid >> 6;
    const int wr = w >> 1, wc = w & 1;
    const int row0 = by * 64, col0 = bx * 128;
    const int MROW = wr * 32;
    const int x7   = lane & 7;

    f32x4 acc[2][4];
#pragma unroll
    for (int m = 0; m < 2; ++m)
#pragma unroll
        for (int n = 0; n < 4; ++n) acc[m][n] = (f32x4){0.f, 0.f, 0.f, 0.f};

    const int lrow = lane >> 3, lcol = (lane & 7) * 8;
    const int arow = tid >> 3, acol8 = (tid & 7) * 8;
    const int aphys = acol8 ^ ((arow & 7) << 3);

    for (int k0 = 0; k0 < 1024; k0 += 64) {
        __syncthreads();
        const int h_ = k0 >> 6;   // uniform per step
#pragma unroll
        for (int p = 0; p < 2; ++p) {
            const int r    = p * 32 + arow;
            const int grow = row0 + r;
            const int b_   = grow >> 10, q_ = grow & 1023;
            const int idx  = (((b_ << 4) + h_) << 10) + q_;
            const float m0 = m_ws[idx], m1 = m_ws[idx + 32768];
            const float l0 = l_ws[idx], l1 = l_ws[idx + 32768];
            const float ms = fmaxf(m0, m1);
            float a0 = exp2f(m0 - ms), a1 = exp2f(m1 - ms);
            const float inv = 1.f / (l0 * a0 + l1 * a1);
            a0 *= inv; a1 *= inv;
            const float* o0 = Op + (size_t)grow * 1024 + k0 + acol8;
            const float* o1 = o0 + (size_t)Bb * QL * Hh;
            float4 x0 = *reinterpret_cast<const float4*>(o0);
            float4 x1 = *reinterpret_cast<const float4*>(o0 + 4);
            float4 y0 = *reinterpret_cast<const float4*>(o1);
            float4 y1 = *reinterpret_cast<const float4*>(o1 + 4);
            float4 f0 = make_float4(x0.x * a0 + y0.x * a1, x0.y * a0 + y0.y * a1,
                                    x0.z * a0 + y0.z * a1, x0.w * a0 + y0.w * a1);
            float4 f1 = make_float4(x1.x * a0 + y1.x * a1, x1.y * a0 + y1.y * a1,
                                    x1.z * a0 + y1.z * a1, x1.w * a0 + y1.w * a1);
            *reinterpret_cast<uint4*>(&As[r * 64 + aphys]) = pack8(f0, f1);
        }
#pragma unroll
        for (int p = 0; p < 4; ++p) {
            const int base = w * 512 + p * 2048;
            const int row  = (base >> 6) + lrow;
            gload16(Bt + (size_t)(col0 + row) * 1024 + k0 + lcol, &Bs[base]);
        }
        __syncthreads();
#pragma unroll
        for (int kk = 0; kk < 2; ++kk) {
            bf16x8 af[2], bfr[4];
            const int G = ((kk * 4 + (lane >> 4)) ^ x7) * 8;
#pragma unroll
            for (int m = 0; m < 2; ++m)
                af[m] = *reinterpret_cast<const bf16x8*>(
                    &As[(MROW + m * 16 + (lane & 15)) * 64 + G]);
#pragma unroll
            for (int n = 0; n < 4; ++n)
                bfr[n] = *reinterpret_cast<const bf16x8*>(
                    &Bs[(wc * 64 + n * 16 + (lane & 15)) * 64 + G]);
#pragma unroll
            for (int m = 0; m < 2; ++m)
#pragma unroll
                for (int n = 0; n < 4; ++n)
                    acc[m][n] = __builtin_amdgcn_mfma_f32_16x16x32_bf16(
                        af[m], bfr[n], acc[m][n], 0, 0, 0);
        }
    }
#pragma unroll
    for (int m = 0; m < 2; ++m)
#pragma unroll
        for (int n = 0; n < 4; ++n) {
            const int gc = col0 + wc * 64 + n * 16 + (lane & 15);
#pragma unroll
            for (int r = 0; r < 4; ++r) {
                const int gr = row0 + MROW + m * 16 + (lane >> 4) * 4 + r;
                C[(size_t)gr * 1024 + gc] = acc[m][n][r];
            }
        }
}

// ---------------------------------------------------------------------------
// Launch.  Workspace:
//   0-16 KT | 16-32 VT | 32-48 Opart | 48-52 Qb | 52-56 wkvT
//  56-58 wqT | 58-60 woutT | 60-60.25 m_ws | 60.25-60.5 l_ws
// ---------------------------------------------------------------------------
extern "C" void kernel_launch(void* const* d_in, const int* in_sizes, int n_in,
                              void* d_out, int out_size, void* d_ws, size_t ws_size,
                              hipStream_t stream) {
    const float* query     = (const float*)d_in[0];
    const float* key_value = (const float*)d_in[1];
    const float* w_q       = (const float*)d_in[2];
    const float* w_kv      = (const float*)d_in[3];
    const float* w_out     = (const float*)d_in[4];
    float* out = (float*)d_out;

    char* ws = (char*)d_ws;
    const size_t MB = 1024 * 1024;
    u16*   KT    = (u16*)(ws);
    u16*   VT    = (u16*)(ws + 16 * MB);
    float* Opart = (float*)(ws + 32 * MB);
    u16*   Qb    = (u16*)(ws + 48 * MB);
    u16*   wkvT  = (u16*)(ws + 52 * MB);
    u16*   wqT   = (u16*)(ws + 56 * MB);
    u16*   woutT = (u16*)(ws + 58 * MB);
    float* m_wsp = (float*)(ws + 60 * MB);
    float* l_wsp = (float*)(ws + 60 * MB + 256 * 1024);

    dim3 blk(256);

    // 1) all weight transposes (swizzled layout) in one launch
    wtrans_all<<<1024, blk, 0, stream>>>(w_q, w_kv, w_out, wqT, wkvT, woutT);

    // 2) Q projection (fused fp32 cast; log2-domain scale)
    qgemm<<<dim3(8, 32), blk, 0, stream>>>(query, wqT, Qb);

    // 3) KV projection (round-8 proven structure; fused blob epilogues)
    kvgemm<<<dim3(16, 64), blk, 0, stream>>>(key_value, wkvT, KT, VT);

    // 4) split-K flash attention (128-key macro-tiles, 1024 blocks)
    attn_mfma<<<dim3(KSPLIT * 512), blk, 0, stream>>>(
        Qb, KT, VT, Opart, m_wsp, l_wsp);

    // 5) output GEMM (fused split-K combine in A-staging)
    ogemm<<<dim3(8, 32), blk, 0, stream>>>(Opart, m_wsp, l_wsp, woutT, out);
}

// Round 11
// 181.611 us; speedup vs baseline: 1.3122x; 1.0575x over previous
//
#include <hip/hip_runtime.h>

// Problem constants (CompactCrossAttention)
#define Bb   2
#define QL   1024
#define KL   4096
#define Hh   1024
#define NH   16
#define HD   64

#define KSPLIT 2
#define CHUNK  (KL / KSPLIT)   // 2048 keys per block
#define NTT    (CHUNK / 64)    // 32 tiles of 64 keys

typedef unsigned short u16;
typedef __attribute__((ext_vector_type(8))) short bf16x8;   // MFMA A/B frag
typedef __attribute__((ext_vector_type(8))) unsigned short usv8;
typedef __attribute__((ext_vector_type(4))) float f32x4;    // MFMA C/D frag

#define QSCALE 0.1803368801111204f   // 0.125 * log2(e): scores in log2 domain
#define RTHR   11.0f                 // defer-max threshold (log2 units)

__device__ __forceinline__ u16 f2bf(float f) {
    union { float f; unsigned int u; } v; v.f = f;
    unsigned int r = (v.u + 0x7FFFu + ((v.u >> 16) & 1u)) >> 16;
    return (u16)r;
}

__device__ __forceinline__ unsigned int cvt_pk_bf16(float lo, float hi) {
    unsigned int r;
    asm("v_cvt_pk_bf16_f32 %0, %1, %2" : "=v"(r) : "v"(lo), "v"(hi));
    return r;
}

__device__ __forceinline__ float max3f(float a, float b, float c) {
    float r;
    asm("v_max3_f32 %0, %1, %2, %3" : "=v"(r) : "v"(a), "v"(b), "v"(c));
    return r;
}

__device__ __forceinline__ void gload16(const void* g, void* l) {
    __builtin_amdgcn_global_load_lds(
        (const __attribute__((address_space(1))) void*)g,
        (__attribute__((address_space(3))) void*)l, 16, 0, 0);
}

// pack 8 fp32 -> 8 bf16 (uint4)
__device__ __forceinline__ uint4 pack8(const float4& f0, const float4& f1) {
    uint4 o;
    o.x = cvt_pk_bf16(f0.x, f0.y);
    o.y = cvt_pk_bf16(f0.z, f0.w);
    o.z = cvt_pk_bf16(f1.x, f1.y);
    o.w = cvt_pk_bf16(f1.z, f1.w);
    return o;
}

// ---------------------------------------------------------------------------
// All three weight transposes (fp32 [R][C] -> bf16 [C][R]) in ONE launch.
// Output rows GRANULE-SWIZZLED: logical k-granule gl at slot gl ^ (n&7).
// ---------------------------------------------------------------------------
__global__ __launch_bounds__(256) void wtrans_all(const float* __restrict__ wq,
                                                  const float* __restrict__ wkv,
                                                  const float* __restrict__ wout,
                                                  u16* __restrict__ wqT,
                                                  u16* __restrict__ wkvT,
                                                  u16* __restrict__ woutT) {
    __shared__ float T[64][65];
    int bid = blockIdx.x;
    const float* in; u16* out; int C;
    if (bid < 256)      { in = wq;   out = wqT;   C = 1024; }
    else if (bid < 768) { in = wkv;  out = wkvT;  C = 2048; bid -= 256; }
    else                { in = wout; out = woutT; C = 1024; bid -= 768; }
    const int nc = C >> 6;
    const int c0 = (bid % nc) * 64;
    const int r0 = (bid / nc) * 64;
    const int t  = threadIdx.x;
    const int tx = t & 15, ty = t >> 4;
#pragma unroll
    for (int p = 0; p < 4; ++p) {
        const int r = ty + p * 16;
        float4 v = *reinterpret_cast<const float4*>(in + (size_t)(r0 + r) * C + c0 + tx * 4);
        T[r][tx * 4 + 0] = v.x; T[r][tx * 4 + 1] = v.y;
        T[r][tx * 4 + 2] = v.z; T[r][tx * 4 + 3] = v.w;
    }
    __syncthreads();
#pragma unroll
    for (int p = 0; p < 4; ++p) {
        const int c = ty + p * 16;
        const int n = c0 + c;
        ushort4 o;
        o.x = f2bf(T[tx * 4 + 0][c]); o.y = f2bf(T[tx * 4 + 1][c]);
        o.z = f2bf(T[tx * 4 + 2][c]); o.w = f2bf(T[tx * 4 + 3][c]);
        const int kb   = r0 + tx * 4;
        const int kout = (kb & ~63) | ((((kb >> 3) & 7) ^ (n & 7)) << 3) | (kb & 7);
        *reinterpret_cast<ushort4*>(out + (size_t)n * 1024 + kout) = o;
    }
}

// ---------------------------------------------------------------------------
// FUSED Q + KV projection GEMM (one launch, 1280 blocks).
// Blocks [0,1024): KV path (128x128 tile) -> pre-swizzled K/V blobs.
// Blocks [1024,1280): Q path (64x128 tile) -> Qb (log2-domain scale).
// Both paths: fp32 A cast-in-staging (XOR-swizzled LDS), gload16 B,
// swizzled fragment reads.  Independent outputs; small Q blocks fill the
// KV tail.
// ---------------------------------------------------------------------------
__global__ __launch_bounds__(256) void qkvgemm(const float* __restrict__ Aq32,
                                               const float* __restrict__ Akv32,
                                               const u16* __restrict__ wqT,
                                               const u16* __restrict__ wkvT,
                                               u16* __restrict__ Qb,
                                               u16* __restrict__ KT,
                                               u16* __restrict__ VT) {
    __shared__ u16 As[128 * 64];
    __shared__ u16 Bs[128 * 64];
    const int tid = threadIdx.x, lane = tid & 63, w = tid >> 6;
    const int wr = w >> 1, wc = w & 1;
    const int x7 = lane & 7;
    const int lrow = lane >> 3, lcol = (lane & 7) * 8;
    const int arow = tid >> 3, acol8 = (tid & 7) * 8;
    const int aphys = acol8 ^ ((arow & 7) << 3);

    if (blockIdx.x < 1024) {
        // ================= KV path =================
        const int id = blockIdx.x;
        const int sw = (id & 7) * 128 + (id >> 3);   // XCD swizzle, nwg=1024
        const int bx = sw % 16, by = sw / 16;
        const int row0 = by * 128, col0 = bx * 128;
        const int MROW = wr * 64;

        f32x4 acc[4][4];
#pragma unroll
        for (int m = 0; m < 4; ++m)
#pragma unroll
            for (int n = 0; n < 4; ++n) acc[m][n] = (f32x4){0.f, 0.f, 0.f, 0.f};

        auto stage = [&](int k0) {
            __syncthreads();
#pragma unroll
            for (int p = 0; p < 4; ++p) {
                const int r = p * 32 + arow;
                const float* src = Akv32 + (size_t)(row0 + r) * 1024 + k0 + acol8;
                float4 f0 = *reinterpret_cast<const float4*>(src);
                float4 f1 = *reinterpret_cast<const float4*>(src + 4);
                *reinterpret_cast<uint4*>(&As[r * 64 + aphys]) = pack8(f0, f1);
            }
#pragma unroll
            for (int p = 0; p < 4; ++p) {
                const int base = w * 512 + p * 2048;
                const int row  = (base >> 6) + lrow;
                gload16(wkvT + (size_t)(col0 + row) * 1024 + k0 + lcol, &Bs[base]);
            }
            __syncthreads();
        };

        if (col0 < 1024) {
            // K orientation: acc = mfma(bfr, af) -> thread owns 4 consecutive d
            for (int k0 = 0; k0 < 1024; k0 += 64) {
                stage(k0);
#pragma unroll
                for (int kk = 0; kk < 2; ++kk) {
                    bf16x8 af[4], bfr[4];
                    const int G = ((kk * 4 + (lane >> 4)) ^ x7) * 8;
#pragma unroll
                    for (int m = 0; m < 4; ++m)
                        af[m] = *reinterpret_cast<const bf16x8*>(
                            &As[(MROW + m * 16 + (lane & 15)) * 64 + G]);
#pragma unroll
                    for (int n = 0; n < 4; ++n)
                        bfr[n] = *reinterpret_cast<const bf16x8*>(
                            &Bs[(wc * 64 + n * 16 + (lane & 15)) * 64 + G]);
#pragma unroll
                    for (int m = 0; m < 4; ++m)
#pragma unroll
                        for (int n = 0; n < 4; ++n)
                            acc[m][n] = __builtin_amdgcn_mfma_f32_16x16x32_bf16(
                                bfr[n], af[m], acc[m][n], 0, 0, 0);
                }
            }
#pragma unroll
            for (int m = 0; m < 4; ++m) {
                const int gr  = row0 + MROW + m * 16 + (lane & 15);
                const int b   = gr >> 12;
                const int k   = gr & 4095;
                const int kt_i = k >> 6, k_in = k & 63;
#pragma unroll
                for (int n = 0; n < 4; ++n) {
                    const int gc0 = col0 + wc * 64 + n * 16 + (lane >> 4) * 4;
                    const int h   = gc0 >> 6, d0 = gc0 & 63;
                    u16* blob = KT + (((size_t)((b << 4) + h) * 64 + kt_i) << 9) * 8;
                    const int og = k_in * 8 + ((d0 >> 3) ^ (k_in & 7));
                    ushort4 pk;
                    pk.x = f2bf(acc[m][n][0]); pk.y = f2bf(acc[m][n][1]);
                    pk.z = f2bf(acc[m][n][2]); pk.w = f2bf(acc[m][n][3]);
                    *reinterpret_cast<ushort4*>(&blob[og * 8 + (d0 & 7)]) = pk;
                }
            }
        } else {
            // V orientation: normal mfma(af, bfr) -> thread owns 4 consecutive k
            for (int k0 = 0; k0 < 1024; k0 += 64) {
                stage(k0);
#pragma unroll
                for (int kk = 0; kk < 2; ++kk) {
                    bf16x8 af[4], bfr[4];
                    const int G = ((kk * 4 + (lane >> 4)) ^ x7) * 8;
#pragma unroll
                    for (int m = 0; m < 4; ++m)
                        af[m] = *reinterpret_cast<const bf16x8*>(
                            &As[(MROW + m * 16 + (lane & 15)) * 64 + G]);
#pragma unroll
                    for (int n = 0; n < 4; ++n)
                        bfr[n] = *reinterpret_cast<const bf16x8*>(
                            &Bs[(wc * 64 + n * 16 + (lane & 15)) * 64 + G]);
#pragma unroll
                    for (int m = 0; m < 4; ++m)
#pragma unroll
                        for (int n = 0; n < 4; ++n)
                            acc[m][n] = __builtin_amdgcn_mfma_f32_16x16x32_bf16(
                                af[m], bfr[n], acc[m][n], 0, 0, 0);
                }
            }
#pragma unroll
            for (int m = 0; m < 4; ++m) {
                const int gr0 = row0 + MROW + m * 16 + (lane >> 4) * 4;
                const int b   = gr0 >> 12;
                const int k   = gr0 & 4095;
                const int kt_i = k >> 6, k_in = k & 63;
#pragma unroll
                for (int n = 0; n < 4; ++n) {
                    const int gc = col0 + wc * 64 + n * 16 + (lane & 15);
                    const int h  = (gc & 1023) >> 6, d = gc & 63;
                    u16* blob = VT + (((size_t)((b << 4) + h) * 64 + kt_i) << 9) * 8;
                    const int og = d * 8 + ((k_in >> 3) ^ (d & 7));
                    ushort4 pk;
                    pk.x = f2bf(acc[m][n][0]); pk.y = f2bf(acc[m][n][1]);
                    pk.z = f2bf(acc[m][n][2]); pk.w = f2bf(acc[m][n][3]);
                    *reinterpret_cast<ushort4*>(&blob[og * 8 + (k_in & 7)]) = pk;
                }
            }
        }
    } else {
        // ================= Q path (64x128 tile) =================
        const int id = blockIdx.x - 1024;
        const int sw = (id & 7) * 32 + (id >> 3);   // XCD swizzle, nwg=256
        const int bx = sw % 8, by = sw / 8;
        const int row0 = by * 64, col0 = bx * 128;
        const int MROW = wr * 32;

        f32x4 acc[2][4];
#pragma unroll
        for (int m = 0; m < 2; ++m)
#pragma unroll
            for (int n = 0; n < 4; ++n) acc[m][n] = (f32x4){0.f, 0.f, 0.f, 0.f};

        for (int k0 = 0; k0 < 1024; k0 += 64) {
            __syncthreads();
#pragma unroll
            for (int p = 0; p < 2; ++p) {
                const int r = p * 32 + arow;
                const float* src = Aq32 + (size_t)(row0 + r) * 1024 + k0 + acol8;
                float4 f0 = *reinterpret_cast<const float4*>(src);
                float4 f1 = *reinterpret_cast<const float4*>(src + 4);
                *reinterpret_cast<uint4*>(&As[r * 64 + aphys]) = pack8(f0, f1);
            }
#pragma unroll
            for (int p = 0; p < 4; ++p) {
                const int base = w * 512 + p * 2048;
                const int row  = (base >> 6) + lrow;
                gload16(wqT + (size_t)(col0 + row) * 1024 + k0 + lcol, &Bs[base]);
            }
            __syncthreads();
#pragma unroll
            for (int kk = 0; kk < 2; ++kk) {
                bf16x8 af[2], bfr[4];
                const int G = ((kk * 4 + (lane >> 4)) ^ x7) * 8;
#pragma unroll
                for (int m = 0; m < 2; ++m)
                    af[m] = *reinterpret_cast<const bf16x8*>(
                        &As[(MROW + m * 16 + (lane & 15)) * 64 + G]);
#pragma unroll
                for (int n = 0; n < 4; ++n)
                    bfr[n] = *reinterpret_cast<const bf16x8*>(
                        &Bs[(wc * 64 + n * 16 + (lane & 15)) * 64 + G]);
#pragma unroll
                for (int m = 0; m < 2; ++m)
#pragma unroll
                    for (int n = 0; n < 4; ++n)
                        acc[m][n] = __builtin_amdgcn_mfma_f32_16x16x32_bf16(
                            af[m], bfr[n], acc[m][n], 0, 0, 0);
            }
        }
#pragma unroll
        for (int m = 0; m < 2; ++m)
#pragma unroll
            for (int n = 0; n < 4; ++n) {
                const int gc = col0 + wc * 64 + n * 16 + (lane & 15);
#pragma unroll
                for (int r = 0; r < 4; ++r) {
                    const int gr = row0 + MROW + m * 16 + (lane >> 4) * 4 + r;
                    Qb[(size_t)gr * 1024 + gc] = f2bf(acc[m][n][r] * QSCALE);
                }
            }
    }
}

// ---------------------------------------------------------------------------
// Split-K bf16 MFMA flash attention — ROUND-8 PROVEN VERSION (79.5 us):
// 32 q-rows per wave (block = 128 q), hoisted LDS base pointers + immediate
// offsets, t-loop unrolled by 2 (buffer index literal), counted vmcnt(4).
// Grid: KSPLIT * B * NH * (QL/128) = 512 blocks, 256 threads.
// ---------------------------------------------------------------------------
__global__ __launch_bounds__(256, 2) void attn_mfma(const u16* __restrict__ Qb,
                                                    const u16* __restrict__ KT,
                                                    const u16* __restrict__ VT2,
                                                    float* __restrict__ Op,
                                                    float* __restrict__ m_ws,
                                                    float* __restrict__ l_ws) {
    __shared__ u16 Ks[2][4096];      // [k][pg*8], pg = g ^ (k&7)
    __shared__ u16 Vs[2][4096];      // [d][pg*8], pg = g ^ (d&7)
    __shared__ u16 Ps[4][2][1024];   // [wave][qh][q*64 + swizzled slot]

    const int bid0 = blockIdx.x;
    const int bid  = (bid0 & 7) * 64 + (bid0 >> 3);   // XCD swizzle (512 blocks)
    const int qb   = bid & 7;
    const int h    = (bid >> 3) & 15;
    const int b    = (bid >> 7) & 1;
    const int c    = bid >> 8;
    const int tid  = threadIdx.x;
    const int lane = tid & 63;
    const int w    = tid >> 6;
    const int q_l  = lane & 15;
    const int g    = lane >> 4;
    const int qs7  = q_l & 7;
    const int q0   = qb * 128;
    const int bh   = b * NH + h;

    // Q B-frags for both q-halves
    bf16x8 qa[2][2];
#pragma unroll
    for (int qh = 0; qh < 2; ++qh) {
        const u16* qsrc = Qb + (size_t)(b * QL + q0 + w * 32 + qh * 16 + q_l) * Hh
                          + h * HD + g * 8;
        qa[qh][0] = *reinterpret_cast<const bf16x8*>(qsrc);
        qa[qh][1] = *reinterpret_cast<const bf16x8*>(qsrc + 32);
    }
    asm volatile("s_waitcnt vmcnt(0)" ::: "memory");

    bf16x8 ones;
#pragma unroll
    for (int e = 0; e < 8; ++e) ones[e] = (short)0x3F80;   // bf16 1.0

    float m_i[2] = {-1e30f, -1e30f};
    f32x4 acc_l[2] = {(f32x4){0.f, 0.f, 0.f, 0.f}, (f32x4){0.f, 0.f, 0.f, 0.f}};
    f32x4 acc_o[2][4];
#pragma unroll
    for (int qh = 0; qh < 2; ++qh)
#pragma unroll
        for (int n = 0; n < 4; ++n) acc_o[qh][n] = (f32x4){0.f, 0.f, 0.f, 0.f};

    // ---- hoisted LDS base pointers (immediate offsets in the loop) ----
    const int koffA = (g ^ qs7) * 8;
    const int koffB = ((g + 4) ^ qs7) * 8;
    const int rowq  = q_l * 64;
    const u16* KsA[2] = { &Ks[0][rowq + koffA], &Ks[1][rowq + koffA] };
    const u16* KsB[2] = { &Ks[0][rowq + koffB], &Ks[1][rowq + koffB] };
    const u16* VsA[2] = { &Vs[0][rowq + koffA], &Vs[1][rowq + koffA] };
    const u16* VsB[2] = { &Vs[0][rowq + koffB], &Vs[1][rowq + koffB] };
    const u16* PsRA = &Ps[w][0][rowq + koffA];   // qh=1 at +1024 elements
    const u16* PsRB = &Ps[w][0][rowq + koffB];
    u16* PsW[4];
#pragma unroll
    for (int n = 0; n < 4; ++n)
        PsW[n] = &Ps[w][0][rowq + (((2 * n + (g >> 1)) ^ qs7) << 3) + (g & 1) * 4];

    // ---- staging pointers: centered for ±2048B immediate offsets ----
    const size_t tb0 = ((size_t)bh * 64 + c * NTT) * 4096;
    const u16* kpt = KT  + tb0 + (size_t)(w * 64 + lane) * 8 + 1024;
    const u16* vpt = VT2 + tb0 + (size_t)(w * 64 + lane) * 8 + 1024;
    u16* kdst[2] = { &Ks[0][w * 512], &Ks[1][w * 512] };
    u16* vdst[2] = { &Vs[0][w * 512], &Vs[1][w * 512] };

    // prologue: stage tile 0 into buf 0 (pointers still at tile 0)
    gload16(kpt - 1024, kdst[0]);
    gload16(kpt + 1024, kdst[0] + 2048);
    gload16(vpt - 1024, vdst[0]);
    gload16(vpt + 1024, vdst[0] + 2048);

    auto tile = [&](int CUR, int t) {
        __builtin_amdgcn_s_barrier();          // prev compute done with buf CUR^1
        if (t + 1 < NTT) {
            kpt += 4096; vpt += 4096;          // advance to tile t+1
            gload16(kpt - 1024, kdst[CUR ^ 1]);
            gload16(kpt + 1024, kdst[CUR ^ 1] + 2048);
            gload16(vpt - 1024, vdst[CUR ^ 1]);
            gload16(vpt + 1024, vdst[CUR ^ 1] + 2048);
            asm volatile("s_waitcnt vmcnt(4)" ::: "memory");   // buf CUR landed
        } else {
            asm volatile("s_waitcnt vmcnt(0)" ::: "memory");
        }
        __builtin_amdgcn_sched_barrier(0);
        __builtin_amdgcn_s_barrier();          // all waves' buf CUR resident

        // QK^T swapped, both q-halves share the K frags
        f32x4 s[2][4];
        __builtin_amdgcn_s_setprio(1);
#pragma unroll
        for (int n = 0; n < 4; ++n) {
            bf16x8 a0 = *reinterpret_cast<const bf16x8*>(KsA[CUR] + n * 1024);
            bf16x8 a1 = *reinterpret_cast<const bf16x8*>(KsB[CUR] + n * 1024);
#pragma unroll
            for (int qh = 0; qh < 2; ++qh) {
                f32x4 z = (f32x4){0.f, 0.f, 0.f, 0.f};
                z = __builtin_amdgcn_mfma_f32_16x16x32_bf16(a0, qa[qh][0], z, 0, 0, 0);
                z = __builtin_amdgcn_mfma_f32_16x16x32_bf16(a1, qa[qh][1], z, 0, 0, 0);
                s[qh][n] = z;
            }
        }
        __builtin_amdgcn_s_setprio(0);

        // online softmax per q-half (log2 domain, defer-max, shared branch)
        float mloc[2];
#pragma unroll
        for (int qh = 0; qh < 2; ++qh) {
            float c1 = max3f(s[qh][0][0], s[qh][0][1], s[qh][0][2]);
            c1 = max3f(c1, s[qh][0][3], s[qh][1][0]);
            c1 = max3f(c1, s[qh][1][1], s[qh][1][2]);
            c1 = fmaxf(c1, s[qh][1][3]);
            float c2 = max3f(s[qh][2][0], s[qh][2][1], s[qh][2][2]);
            c2 = max3f(c2, s[qh][2][3], s[qh][3][0]);
            c2 = max3f(c2, s[qh][3][1], s[qh][3][2]);
            c2 = fmaxf(c2, s[qh][3][3]);
            float m = fmaxf(c1, c2);
            m = fmaxf(m, __shfl_xor(m, 16));
            m = fmaxf(m, __shfl_xor(m, 32));
            mloc[qh] = m;
        }
        if (__any((mloc[0] > m_i[0] + RTHR) || (mloc[1] > m_i[1] + RTHR))) {
#pragma unroll
            for (int qh = 0; qh < 2; ++qh) {
                const float mnew = fmaxf(m_i[qh], mloc[qh]);
                const float al   = exp2f(m_i[qh] - mnew);
                m_i[qh] = mnew;
                acc_l[qh][0] *= al; acc_l[qh][1] *= al;
                acc_l[qh][2] *= al; acc_l[qh][3] *= al;
#pragma unroll
                for (int n = 0; n < 4; ++n) {
                    f32x4 tt = acc_o[qh][n];
                    tt[0] *= al; tt[1] *= al; tt[2] *= al; tt[3] *= al;
                    acc_o[qh][n] = tt;
                }
            }
        }
#pragma unroll
        for (int qh = 0; qh < 2; ++qh) {
#pragma unroll
            for (int n = 0; n < 4; ++n)
#pragma unroll
                for (int r = 0; r < 4; ++r) s[qh][n][r] = exp2f(s[qh][n][r] - m_i[qh]);
            // pack P -> bf16 (swizzled slots, immediate-offset writes)
#pragma unroll
            for (int n = 0; n < 4; ++n) {
                uint2 pk2;
                pk2.x = cvt_pk_bf16(s[qh][n][0], s[qh][n][1]);
                pk2.y = cvt_pk_bf16(s[qh][n][2], s[qh][n][3]);
                *reinterpret_cast<uint2*>(PsW[n] + qh * 1024) = pk2;
            }
        }
        asm volatile("s_waitcnt lgkmcnt(0)" ::: "memory");
        __builtin_amdgcn_sched_barrier(0);

        // PV swapped + l via ones-MFMA; V frags shared across q-halves
        __builtin_amdgcn_s_setprio(1);
#pragma unroll
        for (int kf = 0; kf < 2; ++kf) {
            const u16* pr = (kf == 0) ? PsRA : PsRB;
            bf16x8 pf0 = *reinterpret_cast<const bf16x8*>(pr);
            bf16x8 pf1 = *reinterpret_cast<const bf16x8*>(pr + 1024);
            acc_l[0] = __builtin_amdgcn_mfma_f32_16x16x32_bf16(ones, pf0, acc_l[0], 0, 0, 0);
            acc_l[1] = __builtin_amdgcn_mfma_f32_16x16x32_bf16(ones, pf1, acc_l[1], 0, 0, 0);
#pragma unroll
            for (int n = 0; n < 4; ++n) {
                const u16* vb = (kf == 0) ? VsA[CUR] : VsB[CUR];
                bf16x8 vf = *reinterpret_cast<const bf16x8*>(vb + n * 1024);
                acc_o[0][n] = __builtin_amdgcn_mfma_f32_16x16x32_bf16(vf, pf0, acc_o[0][n], 0, 0, 0);
                acc_o[1][n] = __builtin_amdgcn_mfma_f32_16x16x32_bf16(vf, pf1, acc_o[1][n], 0, 0, 0);
            }
        }
        __builtin_amdgcn_s_setprio(0);
    };

    for (int t = 0; t < NTT; t += 2) {
        tile(0, t);
        tile(1, t + 1);
    }

    // epilogue: unnormalized O (float4 stores) + per-row m,l
#pragma unroll
    for (int qh = 0; qh < 2; ++qh) {
        float* opc = Op + (size_t)c * ((size_t)Bb * QL * Hh)
                     + (size_t)(b * QL + q0 + w * 32 + qh * 16 + q_l) * Hh + h * HD;
#pragma unroll
        for (int n = 0; n < 4; ++n) {
            float4 v = make_float4(acc_o[qh][n][0], acc_o[qh][n][1],
                                   acc_o[qh][n][2], acc_o[qh][n][3]);
            *reinterpret_cast<float4*>(opc + n * 16 + g * 4) = v;
        }
        if (g == 0) {
            const int idx = ((c * Bb + b) * NH + h) * QL + q0 + w * 32 + qh * 16 + q_l;
            m_ws[idx] = m_i[qh];
            l_ws[idx] = acc_l[qh][0];
        }
    }
}

// ---------------------------------------------------------------------------
// Output GEMM with FUSED split-K combine in A-staging.  BMT=64.
// ---------------------------------------------------------------------------
__global__ __launch_bounds__(256) void ogemm(const float* __restrict__ Op,
                                             const float* __restrict__ m_ws,
                                             const float* __restrict__ l_ws,
                                             const u16* __restrict__ Bt,
                                             float* __restrict__ C) {
    __shared__ u16 As[64 * 64];
    __shared__ u16 Bs[128 * 64];
    const int nwg = gridDim.x * gridDim.y;
    const int id  = blockIdx.y * gridDim.x + blockIdx.x;
    const int sw  = (id & 7) * (nwg >> 3) + (id >> 3);
    const int bx  = sw % gridDim.x, by = sw / gridDim.x;
    const int tid = threadIdx.x, lane = tid & 63, w = tid >> 6;
    const int wr = w >> 1, wc = w & 1;
    const int row0 = by * 64, col0 = bx * 128;
    const int MROW = wr * 32;
    const int x7   = lane & 7;

    f32x4 acc[2][4];
#pragma unroll
    for (int m = 0; m < 2; ++m)
#pragma unroll
        for (int n = 0; n < 4; ++n) acc[m][n] = (f32x4){0.f, 0.f, 0.f, 0.f};

    const int lrow = lane >> 3, lcol = (lane & 7) * 8;
    const int arow = tid >> 3, acol8 = (tid & 7) * 8;
    const int aphys = acol8 ^ ((arow & 7) << 3);

    for (int k0 = 0; k0 < 1024; k0 += 64) {
        __syncthreads();
        const int h_ = k0 >> 6;   // uniform per step
#pragma unroll
        for (int p = 0; p < 2; ++p) {
            const int r    = p * 32 + arow;
            const int grow = row0 + r;
            const int b_   = grow >> 10, q_ = grow & 1023;
            const int idx  = (((b_ << 4) + h_) << 10) + q_;
            const float m0 = m_ws[idx], m1 = m_ws[idx + 32768];
            const float l0 = l_ws[idx], l1 = l_ws[idx + 32768];
            const float ms = fmaxf(m0, m1);
            float a0 = exp2f(m0 - ms), a1 = exp2f(m1 - ms);
            const float inv = 1.f / (l0 * a0 + l1 * a1);
            a0 *= inv; a1 *= inv;
            const float* o0 = Op + (size_t)grow * 1024 + k0 + acol8;
            const float* o1 = o0 + (size_t)Bb * QL * Hh;
            float4 x0 = *reinterpret_cast<const float4*>(o0);
            float4 x1 = *reinterpret_cast<const float4*>(o0 + 4);
            float4 y0 = *reinterpret_cast<const float4*>(o1);
            float4 y1 = *reinterpret_cast<const float4*>(o1 + 4);
            float4 f0 = make_float4(x0.x * a0 + y0.x * a1, x0.y * a0 + y0.y * a1,
                                    x0.z * a0 + y0.z * a1, x0.w * a0 + y0.w * a1);
            float4 f1 = make_float4(x1.x * a0 + y1.x * a1, x1.y * a0 + y1.y * a1,
                                    x1.z * a0 + y1.z * a1, x1.w * a0 + y1.w * a1);
            *reinterpret_cast<uint4*>(&As[r * 64 + aphys]) = pack8(f0, f1);
        }
#pragma unroll
        for (int p = 0; p < 4; ++p) {
            const int base = w * 512 + p * 2048;
            const int row  = (base >> 6) + lrow;
            gload16(Bt + (size_t)(col0 + row) * 1024 + k0 + lcol, &Bs[base]);
        }
        __syncthreads();
#pragma unroll
        for (int kk = 0; kk < 2; ++kk) {
            bf16x8 af[2], bfr[4];
            const int G = ((kk * 4 + (lane >> 4)) ^ x7) * 8;
#pragma unroll
            for (int m = 0; m < 2; ++m)
                af[m] = *reinterpret_cast<const bf16x8*>(
                    &As[(MROW + m * 16 + (lane & 15)) * 64 + G]);
#pragma unroll
            for (int n = 0; n < 4; ++n)
                bfr[n] = *reinterpret_cast<const bf16x8*>(
                    &Bs[(wc * 64 + n * 16 + (lane & 15)) * 64 + G]);
#pragma unroll
            for (int m = 0; m < 2; ++m)
#pragma unroll
                for (int n = 0; n < 4; ++n)
                    acc[m][n] = __builtin_amdgcn_mfma_f32_16x16x32_bf16(
                        af[m], bfr[n], acc[m][n], 0, 0, 0);
        }
    }
#pragma unroll
    for (int m = 0; m < 2; ++m)
#pragma unroll
        for (int n = 0; n < 4; ++n) {
            const int gc = col0 + wc * 64 + n * 16 + (lane & 15);
#pragma unroll
            for (int r = 0; r < 4; ++r) {
                const int gr = row0 + MROW + m * 16 + (lane >> 4) * 4 + r;
                C[(size_t)gr * 1024 + gc] = acc[m][n][r];
            }
        }
}

// ---------------------------------------------------------------------------
// Launch.  Workspace:
//   0-16 KT | 16-32 VT | 32-48 Opart | 48-52 Qb | 52-56 wkvT
//  56-58 wqT | 58-60 woutT | 60-60.25 m_ws | 60.25-60.5 l_ws
// ---------------------------------------------------------------------------
extern "C" void kernel_launch(void* const* d_in, const int* in_sizes, int n_in,
                              void* d_out, int out_size, void* d_ws, size_t ws_size,
                              hipStream_t stream) {
    const float* query     = (const float*)d_in[0];
    const float* key_value = (const float*)d_in[1];
    const float* w_q       = (const float*)d_in[2];
    const float* w_kv      = (const float*)d_in[3];
    const float* w_out     = (const float*)d_in[4];
    float* out = (float*)d_out;

    char* ws = (char*)d_ws;
    const size_t MB = 1024 * 1024;
    u16*   KT    = (u16*)(ws);
    u16*   VT    = (u16*)(ws + 16 * MB);
    float* Opart = (float*)(ws + 32 * MB);
    u16*   Qb    = (u16*)(ws + 48 * MB);
    u16*   wkvT  = (u16*)(ws + 52 * MB);
    u16*   wqT   = (u16*)(ws + 56 * MB);
    u16*   woutT = (u16*)(ws + 58 * MB);
    float* m_wsp = (float*)(ws + 60 * MB);
    float* l_wsp = (float*)(ws + 60 * MB + 256 * 1024);

    dim3 blk(256);

    // 1) all weight transposes (swizzled layout) in one launch
    wtrans_all<<<1024, blk, 0, stream>>>(w_q, w_kv, w_out, wqT, wkvT, woutT);

    // 2) FUSED Q + KV projections (1280 blocks; Q blocks fill KV tail)
    qkvgemm<<<1280, blk, 0, stream>>>(query, key_value, wqT, wkvT, Qb, KT, VT);

    // 3) split-K flash attention (round-8 proven kernel, 512 blocks)
    attn_mfma<<<dim3(KSPLIT * 256), blk, 0, stream>>>(
        Qb, KT, VT, Opart, m_wsp, l_wsp);

    // 4) output GEMM (fused split-K combine in A-staging)
    ogemm<<<dim3(8, 32), blk, 0, stream>>>(Opart, m_wsp, l_wsp, woutT, out);
}

// Round 12
// 174.454 us; speedup vs baseline: 1.3660x; 1.0410x over previous
//
#include <hip/hip_runtime.h>

// Problem constants (CompactCrossAttention)
#define Bb   2
#define QL   1024
#define KL   4096
#define Hh   1024
#define NH   16
#define HD   64

#define KSPLIT 2
#define CHUNK  (KL / KSPLIT)   // 2048 keys per block
#define NTT    (CHUNK / 64)    // 32 tiles of 64 keys

typedef unsigned short u16;
typedef __attribute__((ext_vector_type(8))) short bf16x8;   // MFMA A/B frag
typedef __attribute__((ext_vector_type(8))) unsigned short usv8;
typedef __attribute__((ext_vector_type(4))) float f32x4;    // MFMA C/D frag

#define QSCALE 0.1803368801111204f   // 0.125 * log2(e): scores in log2 domain
#define RTHR   11.0f                 // defer-max threshold (log2 units)

__device__ __forceinline__ u16 f2bf(float f) {
    union { float f; unsigned int u; } v; v.f = f;
    unsigned int r = (v.u + 0x7FFFu + ((v.u >> 16) & 1u)) >> 16;
    return (u16)r;
}

__device__ __forceinline__ unsigned int cvt_pk_bf16(float lo, float hi) {
    unsigned int r;
    asm("v_cvt_pk_bf16_f32 %0, %1, %2" : "=v"(r) : "v"(lo), "v"(hi));
    return r;
}

__device__ __forceinline__ float max3f(float a, float b, float c) {
    float r;
    asm("v_max3_f32 %0, %1, %2, %3" : "=v"(r) : "v"(a), "v"(b), "v"(c));
    return r;
}

__device__ __forceinline__ void gload16(const void* g, void* l) {
    __builtin_amdgcn_global_load_lds(
        (const __attribute__((address_space(1))) void*)g,
        (__attribute__((address_space(3))) void*)l, 16, 0, 0);
}

// pack 8 fp32 -> 8 bf16 (uint4)
__device__ __forceinline__ uint4 pack8(const float4& f0, const float4& f1) {
    uint4 o;
    o.x = cvt_pk_bf16(f0.x, f0.y);
    o.y = cvt_pk_bf16(f0.z, f0.w);
    o.z = cvt_pk_bf16(f1.x, f1.y);
    o.w = cvt_pk_bf16(f1.z, f1.w);
    return o;
}

// ---------------------------------------------------------------------------
// Activation casts (fp32 -> bf16), one launch.
// Blocks [0,1024): query -> qbf (2M elems).  [1024,5120): key_value -> kvbf.
// ---------------------------------------------------------------------------
__global__ __launch_bounds__(256) void cast_all(const float* __restrict__ q,
                                                const float* __restrict__ kv,
                                                u16* __restrict__ qb,
                                                u16* __restrict__ kvb) {
    int bid = blockIdx.x;
    const float* in; u16* out;
    if (bid < 1024) { in = q;  out = qb;  }
    else            { in = kv; out = kvb; bid -= 1024; }
    const size_t i = ((size_t)bid * 256 + threadIdx.x) * 8;
    float4 f0 = *reinterpret_cast<const float4*>(in + i);
    float4 f1 = *reinterpret_cast<const float4*>(in + i + 4);
    *reinterpret_cast<uint4*>(out + i) = pack8(f0, f1);
}

// ---------------------------------------------------------------------------
// All three weight transposes (fp32 [R][C] -> bf16 [C][R]) in ONE launch.
// Output rows GRANULE-SWIZZLED: logical k-granule gl at slot gl ^ (n&7).
// ---------------------------------------------------------------------------
__global__ __launch_bounds__(256) void wtrans_all(const float* __restrict__ wq,
                                                  const float* __restrict__ wkv,
                                                  const float* __restrict__ wout,
                                                  u16* __restrict__ wqT,
                                                  u16* __restrict__ wkvT,
                                                  u16* __restrict__ woutT) {
    __shared__ float T[64][65];
    int bid = blockIdx.x;
    const float* in; u16* out; int C;
    if (bid < 256)      { in = wq;   out = wqT;   C = 1024; }
    else if (bid < 768) { in = wkv;  out = wkvT;  C = 2048; bid -= 256; }
    else                { in = wout; out = woutT; C = 1024; bid -= 768; }
    const int nc = C >> 6;
    const int c0 = (bid % nc) * 64;
    const int r0 = (bid / nc) * 64;
    const int t  = threadIdx.x;
    const int tx = t & 15, ty = t >> 4;
#pragma unroll
    for (int p = 0; p < 4; ++p) {
        const int r = ty + p * 16;
        float4 v = *reinterpret_cast<const float4*>(in + (size_t)(r0 + r) * C + c0 + tx * 4);
        T[r][tx * 4 + 0] = v.x; T[r][tx * 4 + 1] = v.y;
        T[r][tx * 4 + 2] = v.z; T[r][tx * 4 + 3] = v.w;
    }
    __syncthreads();
#pragma unroll
    for (int p = 0; p < 4; ++p) {
        const int c = ty + p * 16;
        const int n = c0 + c;
        ushort4 o;
        o.x = f2bf(T[tx * 4 + 0][c]); o.y = f2bf(T[tx * 4 + 1][c]);
        o.z = f2bf(T[tx * 4 + 2][c]); o.w = f2bf(T[tx * 4 + 3][c]);
        const int kb   = r0 + tx * 4;
        const int kout = (kb & ~63) | ((((kb >> 3) & 7) ^ (n & 7)) << 3) | (kb & 7);
        *reinterpret_cast<ushort4*>(out + (size_t)n * 1024 + kout) = o;
    }
}

// ---------------------------------------------------------------------------
// FUSED Q + KV projection GEMM — pure m97 structure: BOTH operands staged
// via global_load_lds.  A (bf16 activations) uses a per-lane XOR'd source
// granule so the linear LDS write lands in the swizzled layout; B (weights)
// is pre-swizzled in wtrans_all.  Zero VALU staging.
// Blocks [0,1024): KV path (128x128).  [1024,1280): Q path (64x128).
// ---------------------------------------------------------------------------
__global__ __launch_bounds__(256) void qkvgemm(const u16* __restrict__ Aq,
                                               const u16* __restrict__ Akv,
                                               const u16* __restrict__ wqT,
                                               const u16* __restrict__ wkvT,
                                               u16* __restrict__ Qb,
                                               u16* __restrict__ KT,
                                               u16* __restrict__ VT) {
    __shared__ u16 As[128 * 64];
    __shared__ u16 Bs[128 * 64];
    const int tid = threadIdx.x, lane = tid & 63, w = tid >> 6;
    const int wr = w >> 1, wc = w & 1;
    const int x7 = lane & 7;
    const int lrow = lane >> 3, lcol = (lane & 7) * 8;
    const int swcol = lcol ^ ((lrow & 7) << 3);   // A source granule XOR

    if (blockIdx.x < 1024) {
        // ================= KV path =================
        const int id = blockIdx.x;
        const int sw = (id & 7) * 128 + (id >> 3);   // XCD swizzle, nwg=1024
        const int bx = sw % 16, by = sw / 16;
        const int row0 = by * 128, col0 = bx * 128;
        const int MROW = wr * 64;

        f32x4 acc[4][4];
#pragma unroll
        for (int m = 0; m < 4; ++m)
#pragma unroll
            for (int n = 0; n < 4; ++n) acc[m][n] = (f32x4){0.f, 0.f, 0.f, 0.f};

        auto stage = [&](int k0) {
            __syncthreads();
#pragma unroll
            for (int p = 0; p < 4; ++p) {
                const int base = w * 512 + p * 2048;
                const int row  = (base >> 6) + lrow;
                gload16(Akv + (size_t)(row0 + row) * 1024 + k0 + swcol, &As[base]);
                gload16(wkvT + (size_t)(col0 + row) * 1024 + k0 + lcol, &Bs[base]);
            }
            __syncthreads();
        };

        if (col0 < 1024) {
            // K orientation: acc = mfma(bfr, af) -> thread owns 4 consecutive d
            for (int k0 = 0; k0 < 1024; k0 += 64) {
                stage(k0);
#pragma unroll
                for (int kk = 0; kk < 2; ++kk) {
                    bf16x8 af[4], bfr[4];
                    const int G = ((kk * 4 + (lane >> 4)) ^ x7) * 8;
#pragma unroll
                    for (int m = 0; m < 4; ++m)
                        af[m] = *reinterpret_cast<const bf16x8*>(
                            &As[(MROW + m * 16 + (lane & 15)) * 64 + G]);
#pragma unroll
                    for (int n = 0; n < 4; ++n)
                        bfr[n] = *reinterpret_cast<const bf16x8*>(
                            &Bs[(wc * 64 + n * 16 + (lane & 15)) * 64 + G]);
#pragma unroll
                    for (int m = 0; m < 4; ++m)
#pragma unroll
                        for (int n = 0; n < 4; ++n)
                            acc[m][n] = __builtin_amdgcn_mfma_f32_16x16x32_bf16(
                                bfr[n], af[m], acc[m][n], 0, 0, 0);
                }
            }
#pragma unroll
            for (int m = 0; m < 4; ++m) {
                const int gr  = row0 + MROW + m * 16 + (lane & 15);
                const int b   = gr >> 12;
                const int k   = gr & 4095;
                const int kt_i = k >> 6, k_in = k & 63;
#pragma unroll
                for (int n = 0; n < 4; ++n) {
                    const int gc0 = col0 + wc * 64 + n * 16 + (lane >> 4) * 4;
                    const int h   = gc0 >> 6, d0 = gc0 & 63;
                    u16* blob = KT + (((size_t)((b << 4) + h) * 64 + kt_i) << 9) * 8;
                    const int og = k_in * 8 + ((d0 >> 3) ^ (k_in & 7));
                    ushort4 pk;
                    pk.x = f2bf(acc[m][n][0]); pk.y = f2bf(acc[m][n][1]);
                    pk.z = f2bf(acc[m][n][2]); pk.w = f2bf(acc[m][n][3]);
                    *reinterpret_cast<ushort4*>(&blob[og * 8 + (d0 & 7)]) = pk;
                }
            }
        } else {
            // V orientation: normal mfma(af, bfr) -> thread owns 4 consecutive k
            for (int k0 = 0; k0 < 1024; k0 += 64) {
                stage(k0);
#pragma unroll
                for (int kk = 0; kk < 2; ++kk) {
                    bf16x8 af[4], bfr[4];
                    const int G = ((kk * 4 + (lane >> 4)) ^ x7) * 8;
#pragma unroll
                    for (int m = 0; m < 4; ++m)
                        af[m] = *reinterpret_cast<const bf16x8*>(
                            &As[(MROW + m * 16 + (lane & 15)) * 64 + G]);
#pragma unroll
                    for (int n = 0; n < 4; ++n)
                        bfr[n] = *reinterpret_cast<const bf16x8*>(
                            &Bs[(wc * 64 + n * 16 + (lane & 15)) * 64 + G]);
#pragma unroll
                    for (int m = 0; m < 4; ++m)
#pragma unroll
                        for (int n = 0; n < 4; ++n)
                            acc[m][n] = __builtin_amdgcn_mfma_f32_16x16x32_bf16(
                                af[m], bfr[n], acc[m][n], 0, 0, 0);
                }
            }
#pragma unroll
            for (int m = 0; m < 4; ++m) {
                const int gr0 = row0 + MROW + m * 16 + (lane >> 4) * 4;
                const int b   = gr0 >> 12;
                const int k   = gr0 & 4095;
                const int kt_i = k >> 6, k_in = k & 63;
#pragma unroll
                for (int n = 0; n < 4; ++n) {
                    const int gc = col0 + wc * 64 + n * 16 + (lane & 15);
                    const int h  = (gc & 1023) >> 6, d = gc & 63;
                    u16* blob = VT + (((size_t)((b << 4) + h) * 64 + kt_i) << 9) * 8;
                    const int og = d * 8 + ((k_in >> 3) ^ (d & 7));
                    ushort4 pk;
                    pk.x = f2bf(acc[m][n][0]); pk.y = f2bf(acc[m][n][1]);
                    pk.z = f2bf(acc[m][n][2]); pk.w = f2bf(acc[m][n][3]);
                    *reinterpret_cast<ushort4*>(&blob[og * 8 + (k_in & 7)]) = pk;
                }
            }
        }
    } else {
        // ================= Q path (64x128 tile) =================
        const int id = blockIdx.x - 1024;
        const int sw = (id & 7) * 32 + (id >> 3);   // XCD swizzle, nwg=256
        const int bx = sw % 8, by = sw / 8;
        const int row0 = by * 64, col0 = bx * 128;
        const int MROW = wr * 32;

        f32x4 acc[2][4];
#pragma unroll
        for (int m = 0; m < 2; ++m)
#pragma unroll
            for (int n = 0; n < 4; ++n) acc[m][n] = (f32x4){0.f, 0.f, 0.f, 0.f};

        for (int k0 = 0; k0 < 1024; k0 += 64) {
            __syncthreads();
#pragma unroll
            for (int p = 0; p < 2; ++p) {
                const int base = w * 512 + p * 2048;
                const int row  = (base >> 6) + lrow;
                gload16(Aq + (size_t)(row0 + row) * 1024 + k0 + swcol, &As[base]);
            }
#pragma unroll
            for (int p = 0; p < 4; ++p) {
                const int base = w * 512 + p * 2048;
                const int row  = (base >> 6) + lrow;
                gload16(wqT + (size_t)(col0 + row) * 1024 + k0 + lcol, &Bs[base]);
            }
            __syncthreads();
#pragma unroll
            for (int kk = 0; kk < 2; ++kk) {
                bf16x8 af[2], bfr[4];
                const int G = ((kk * 4 + (lane >> 4)) ^ x7) * 8;
#pragma unroll
                for (int m = 0; m < 2; ++m)
                    af[m] = *reinterpret_cast<const bf16x8*>(
                        &As[(MROW + m * 16 + (lane & 15)) * 64 + G]);
#pragma unroll
                for (int n = 0; n < 4; ++n)
                    bfr[n] = *reinterpret_cast<const bf16x8*>(
                        &Bs[(wc * 64 + n * 16 + (lane & 15)) * 64 + G]);
#pragma unroll
                for (int m = 0; m < 2; ++m)
#pragma unroll
                    for (int n = 0; n < 4; ++n)
                        acc[m][n] = __builtin_amdgcn_mfma_f32_16x16x32_bf16(
                            af[m], bfr[n], acc[m][n], 0, 0, 0);
            }
        }
#pragma unroll
        for (int m = 0; m < 2; ++m)
#pragma unroll
            for (int n = 0; n < 4; ++n) {
                const int gc = col0 + wc * 64 + n * 16 + (lane & 15);
#pragma unroll
                for (int r = 0; r < 4; ++r) {
                    const int gr = row0 + MROW + m * 16 + (lane >> 4) * 4 + r;
                    Qb[(size_t)gr * 1024 + gc] = f2bf(acc[m][n][r] * QSCALE);
                }
            }
    }
}

// ---------------------------------------------------------------------------
// Split-K bf16 MFMA flash attention — ROUND-8 PROVEN VERSION (79.5 us):
// 32 q-rows per wave (block = 128 q), hoisted LDS base pointers + immediate
// offsets, t-loop unrolled by 2 (buffer index literal), counted vmcnt(4).
// Grid: KSPLIT * B * NH * (QL/128) = 512 blocks, 256 threads.
// ---------------------------------------------------------------------------
__global__ __launch_bounds__(256, 2) void attn_mfma(const u16* __restrict__ Qb,
                                                    const u16* __restrict__ KT,
                                                    const u16* __restrict__ VT2,
                                                    float* __restrict__ Op,
                                                    float* __restrict__ m_ws,
                                                    float* __restrict__ l_ws) {
    __shared__ u16 Ks[2][4096];      // [k][pg*8], pg = g ^ (k&7)
    __shared__ u16 Vs[2][4096];      // [d][pg*8], pg = g ^ (d&7)
    __shared__ u16 Ps[4][2][1024];   // [wave][qh][q*64 + swizzled slot]

    const int bid0 = blockIdx.x;
    const int bid  = (bid0 & 7) * 64 + (bid0 >> 3);   // XCD swizzle (512 blocks)
    const int qb   = bid & 7;
    const int h    = (bid >> 3) & 15;
    const int b    = (bid >> 7) & 1;
    const int c    = bid >> 8;
    const int tid  = threadIdx.x;
    const int lane = tid & 63;
    const int w    = tid >> 6;
    const int q_l  = lane & 15;
    const int g    = lane >> 4;
    const int qs7  = q_l & 7;
    const int q0   = qb * 128;
    const int bh   = b * NH + h;

    // Q B-frags for both q-halves
    bf16x8 qa[2][2];
#pragma unroll
    for (int qh = 0; qh < 2; ++qh) {
        const u16* qsrc = Qb + (size_t)(b * QL + q0 + w * 32 + qh * 16 + q_l) * Hh
                          + h * HD + g * 8;
        qa[qh][0] = *reinterpret_cast<const bf16x8*>(qsrc);
        qa[qh][1] = *reinterpret_cast<const bf16x8*>(qsrc + 32);
    }
    asm volatile("s_waitcnt vmcnt(0)" ::: "memory");

    bf16x8 ones;
#pragma unroll
    for (int e = 0; e < 8; ++e) ones[e] = (short)0x3F80;   // bf16 1.0

    float m_i[2] = {-1e30f, -1e30f};
    f32x4 acc_l[2] = {(f32x4){0.f, 0.f, 0.f, 0.f}, (f32x4){0.f, 0.f, 0.f, 0.f}};
    f32x4 acc_o[2][4];
#pragma unroll
    for (int qh = 0; qh < 2; ++qh)
#pragma unroll
        for (int n = 0; n < 4; ++n) acc_o[qh][n] = (f32x4){0.f, 0.f, 0.f, 0.f};

    // ---- hoisted LDS base pointers (immediate offsets in the loop) ----
    const int koffA = (g ^ qs7) * 8;
    const int koffB = ((g + 4) ^ qs7) * 8;
    const int rowq  = q_l * 64;
    const u16* KsA[2] = { &Ks[0][rowq + koffA], &Ks[1][rowq + koffA] };
    const u16* KsB[2] = { &Ks[0][rowq + koffB], &Ks[1][rowq + koffB] };
    const u16* VsA[2] = { &Vs[0][rowq + koffA], &Vs[1][rowq + koffA] };
    const u16* VsB[2] = { &Vs[0][rowq + koffB], &Vs[1][rowq + koffB] };
    const u16* PsRA = &Ps[w][0][rowq + koffA];   // qh=1 at +1024 elements
    const u16* PsRB = &Ps[w][0][rowq + koffB];
    u16* PsW[4];
#pragma unroll
    for (int n = 0; n < 4; ++n)
        PsW[n] = &Ps[w][0][rowq + (((2 * n + (g >> 1)) ^ qs7) << 3) + (g & 1) * 4];

    // ---- staging pointers: centered for ±2048B immediate offsets ----
    const size_t tb0 = ((size_t)bh * 64 + c * NTT) * 4096;
    const u16* kpt = KT  + tb0 + (size_t)(w * 64 + lane) * 8 + 1024;
    const u16* vpt = VT2 + tb0 + (size_t)(w * 64 + lane) * 8 + 1024;
    u16* kdst[2] = { &Ks[0][w * 512], &Ks[1][w * 512] };
    u16* vdst[2] = { &Vs[0][w * 512], &Vs[1][w * 512] };

    // prologue: stage tile 0 into buf 0 (pointers still at tile 0)
    gload16(kpt - 1024, kdst[0]);
    gload16(kpt + 1024, kdst[0] + 2048);
    gload16(vpt - 1024, vdst[0]);
    gload16(vpt + 1024, vdst[0] + 2048);

    auto tile = [&](int CUR, int t) {
        __builtin_amdgcn_s_barrier();          // prev compute done with buf CUR^1
        if (t + 1 < NTT) {
            kpt += 4096; vpt += 4096;          // advance to tile t+1
            gload16(kpt - 1024, kdst[CUR ^ 1]);
            gload16(kpt + 1024, kdst[CUR ^ 1] + 2048);
            gload16(vpt - 1024, vdst[CUR ^ 1]);
            gload16(vpt + 1024, vdst[CUR ^ 1] + 2048);
            asm volatile("s_waitcnt vmcnt(4)" ::: "memory");   // buf CUR landed
        } else {
            asm volatile("s_waitcnt vmcnt(0)" ::: "memory");
        }
        __builtin_amdgcn_sched_barrier(0);
        __builtin_amdgcn_s_barrier();          // all waves' buf CUR resident

        // QK^T swapped, both q-halves share the K frags
        f32x4 s[2][4];
        __builtin_amdgcn_s_setprio(1);
#pragma unroll
        for (int n = 0; n < 4; ++n) {
            bf16x8 a0 = *reinterpret_cast<const bf16x8*>(KsA[CUR] + n * 1024);
            bf16x8 a1 = *reinterpret_cast<const bf16x8*>(KsB[CUR] + n * 1024);
#pragma unroll
            for (int qh = 0; qh < 2; ++qh) {
                f32x4 z = (f32x4){0.f, 0.f, 0.f, 0.f};
                z = __builtin_amdgcn_mfma_f32_16x16x32_bf16(a0, qa[qh][0], z, 0, 0, 0);
                z = __builtin_amdgcn_mfma_f32_16x16x32_bf16(a1, qa[qh][1], z, 0, 0, 0);
                s[qh][n] = z;
            }
        }
        __builtin_amdgcn_s_setprio(0);

        // online softmax per q-half (log2 domain, defer-max, shared branch)
        float mloc[2];
#pragma unroll
        for (int qh = 0; qh < 2; ++qh) {
            float c1 = max3f(s[qh][0][0], s[qh][0][1], s[qh][0][2]);
            c1 = max3f(c1, s[qh][0][3], s[qh][1][0]);
            c1 = max3f(c1, s[qh][1][1], s[qh][1][2]);
            c1 = fmaxf(c1, s[qh][1][3]);
            float c2 = max3f(s[qh][2][0], s[qh][2][1], s[qh][2][2]);
            c2 = max3f(c2, s[qh][2][3], s[qh][3][0]);
            c2 = max3f(c2, s[qh][3][1], s[qh][3][2]);
            c2 = fmaxf(c2, s[qh][3][3]);
            float m = fmaxf(c1, c2);
            m = fmaxf(m, __shfl_xor(m, 16));
            m = fmaxf(m, __shfl_xor(m, 32));
            mloc[qh] = m;
        }
        if (__any((mloc[0] > m_i[0] + RTHR) || (mloc[1] > m_i[1] + RTHR))) {
#pragma unroll
            for (int qh = 0; qh < 2; ++qh) {
                const float mnew = fmaxf(m_i[qh], mloc[qh]);
                const float al   = exp2f(m_i[qh] - mnew);
                m_i[qh] = mnew;
                acc_l[qh][0] *= al; acc_l[qh][1] *= al;
                acc_l[qh][2] *= al; acc_l[qh][3] *= al;
#pragma unroll
                for (int n = 0; n < 4; ++n) {
                    f32x4 tt = acc_o[qh][n];
                    tt[0] *= al; tt[1] *= al; tt[2] *= al; tt[3] *= al;
                    acc_o[qh][n] = tt;
                }
            }
        }
#pragma unroll
        for (int qh = 0; qh < 2; ++qh) {
#pragma unroll
            for (int n = 0; n < 4; ++n)
#pragma unroll
                for (int r = 0; r < 4; ++r) s[qh][n][r] = exp2f(s[qh][n][r] - m_i[qh]);
            // pack P -> bf16 (swizzled slots, immediate-offset writes)
#pragma unroll
            for (int n = 0; n < 4; ++n) {
                uint2 pk2;
                pk2.x = cvt_pk_bf16(s[qh][n][0], s[qh][n][1]);
                pk2.y = cvt_pk_bf16(s[qh][n][2], s[qh][n][3]);
                *reinterpret_cast<uint2*>(PsW[n] + qh * 1024) = pk2;
            }
        }
        asm volatile("s_waitcnt lgkmcnt(0)" ::: "memory");
        __builtin_amdgcn_sched_barrier(0);

        // PV swapped + l via ones-MFMA; V frags shared across q-halves
        __builtin_amdgcn_s_setprio(1);
#pragma unroll
        for (int kf = 0; kf < 2; ++kf) {
            const u16* pr = (kf == 0) ? PsRA : PsRB;
            bf16x8 pf0 = *reinterpret_cast<const bf16x8*>(pr);
            bf16x8 pf1 = *reinterpret_cast<const bf16x8*>(pr + 1024);
            acc_l[0] = __builtin_amdgcn_mfma_f32_16x16x32_bf16(ones, pf0, acc_l[0], 0, 0, 0);
            acc_l[1] = __builtin_amdgcn_mfma_f32_16x16x32_bf16(ones, pf1, acc_l[1], 0, 0, 0);
#pragma unroll
            for (int n = 0; n < 4; ++n) {
                const u16* vb = (kf == 0) ? VsA[CUR] : VsB[CUR];
                bf16x8 vf = *reinterpret_cast<const bf16x8*>(vb + n * 1024);
                acc_o[0][n] = __builtin_amdgcn_mfma_f32_16x16x32_bf16(vf, pf0, acc_o[0][n], 0, 0, 0);
                acc_o[1][n] = __builtin_amdgcn_mfma_f32_16x16x32_bf16(vf, pf1, acc_o[1][n], 0, 0, 0);
            }
        }
        __builtin_amdgcn_s_setprio(0);
    };

    for (int t = 0; t < NTT; t += 2) {
        tile(0, t);
        tile(1, t + 1);
    }

    // epilogue: unnormalized O (float4 stores) + per-row m,l
#pragma unroll
    for (int qh = 0; qh < 2; ++qh) {
        float* opc = Op + (size_t)c * ((size_t)Bb * QL * Hh)
                     + (size_t)(b * QL + q0 + w * 32 + qh * 16 + q_l) * Hh + h * HD;
#pragma unroll
        for (int n = 0; n < 4; ++n) {
            float4 v = make_float4(acc_o[qh][n][0], acc_o[qh][n][1],
                                   acc_o[qh][n][2], acc_o[qh][n][3]);
            *reinterpret_cast<float4*>(opc + n * 16 + g * 4) = v;
        }
        if (g == 0) {
            const int idx = ((c * Bb + b) * NH + h) * QL + q0 + w * 32 + qh * 16 + q_l;
            m_ws[idx] = m_i[qh];
            l_ws[idx] = acc_l[qh][0];
        }
    }
}

// ---------------------------------------------------------------------------
// Output GEMM with FUSED split-K combine in A-staging.  BMT=64.
// ---------------------------------------------------------------------------
__global__ __launch_bounds__(256) void ogemm(const float* __restrict__ Op,
                                             const float* __restrict__ m_ws,
                                             const float* __restrict__ l_ws,
                                             const u16* __restrict__ Bt,
                                             float* __restrict__ C) {
    __shared__ u16 As[64 * 64];
    __shared__ u16 Bs[128 * 64];
    const int nwg = gridDim.x * gridDim.y;
    const int id  = blockIdx.y * gridDim.x + blockIdx.x;
    const int sw  = (id & 7) * (nwg >> 3) + (id >> 3);
    const int bx  = sw % gridDim.x, by = sw / gridDim.x;
    const int tid = threadIdx.x, lane = tid & 63, w = tid >> 6;
    const int wr = w >> 1, wc = w & 1;
    const int row0 = by * 64, col0 = bx * 128;
    const int MROW = wr * 32;
    const int x7   = lane & 7;

    f32x4 acc[2][4];
#pragma unroll
    for (int m = 0; m < 2; ++m)
#pragma unroll
        for (int n = 0; n < 4; ++n) acc[m][n] = (f32x4){0.f, 0.f, 0.f, 0.f};

    const int lrow = lane >> 3, lcol = (lane & 7) * 8;
    const int arow = tid >> 3, acol8 = (tid & 7) * 8;
    const int aphys = acol8 ^ ((arow & 7) << 3);

    for (int k0 = 0; k0 < 1024; k0 += 64) {
        __syncthreads();
        const int h_ = k0 >> 6;   // uniform per step
#pragma unroll
        for (int p = 0; p < 2; ++p) {
            const int r    = p * 32 + arow;
            const int grow = row0 + r;
            const int b_   = grow >> 10, q_ = grow & 1023;
            const int idx  = (((b_ << 4) + h_) << 10) + q_;
            const float m0 = m_ws[idx], m1 = m_ws[idx + 32768];
            const float l0 = l_ws[idx], l1 = l_ws[idx + 32768];
            const float ms = fmaxf(m0, m1);
            float a0 = exp2f(m0 - ms), a1 = exp2f(m1 - ms);
            const float inv = 1.f / (l0 * a0 + l1 * a1);
            a0 *= inv; a1 *= inv;
            const float* o0 = Op + (size_t)grow * 1024 + k0 + acol8;
            const float* o1 = o0 + (size_t)Bb * QL * Hh;
            float4 x0 = *reinterpret_cast<const float4*>(o0);
            float4 x1 = *reinterpret_cast<const float4*>(o0 + 4);
            float4 y0 = *reinterpret_cast<const float4*>(o1);
            float4 y1 = *reinterpret_cast<const float4*>(o1 + 4);
            float4 f0 = make_float4(x0.x * a0 + y0.x * a1, x0.y * a0 + y0.y * a1,
                                    x0.z * a0 + y0.z * a1, x0.w * a0 + y0.w * a1);
            float4 f1 = make_float4(x1.x * a0 + y1.x * a1, x1.y * a0 + y1.y * a1,
                                    x1.z * a0 + y1.z * a1, x1.w * a0 + y1.w * a1);
            *reinterpret_cast<uint4*>(&As[r * 64 + aphys]) = pack8(f0, f1);
        }
#pragma unroll
        for (int p = 0; p < 4; ++p) {
            const int base = w * 512 + p * 2048;
            const int row  = (base >> 6) + lrow;
            gload16(Bt + (size_t)(col0 + row) * 1024 + k0 + lcol, &Bs[base]);
        }
        __syncthreads();
#pragma unroll
        for (int kk = 0; kk < 2; ++kk) {
            bf16x8 af[2], bfr[4];
            const int G = ((kk * 4 + (lane >> 4)) ^ x7) * 8;
#pragma unroll
            for (int m = 0; m < 2; ++m)
                af[m] = *reinterpret_cast<const bf16x8*>(
                    &As[(MROW + m * 16 + (lane & 15)) * 64 + G]);
#pragma unroll
            for (int n = 0; n < 4; ++n)
                bfr[n] = *reinterpret_cast<const bf16x8*>(
                    &Bs[(wc * 64 + n * 16 + (lane & 15)) * 64 + G]);
#pragma unroll
            for (int m = 0; m < 2; ++m)
#pragma unroll
                for (int n = 0; n < 4; ++n)
                    acc[m][n] = __builtin_amdgcn_mfma_f32_16x16x32_bf16(
                        af[m], bfr[n], acc[m][n], 0, 0, 0);
        }
    }
#pragma unroll
    for (int m = 0; m < 2; ++m)
#pragma unroll
        for (int n = 0; n < 4; ++n) {
            const int gc = col0 + wc * 64 + n * 16 + (lane & 15);
#pragma unroll
            for (int r = 0; r < 4; ++r) {
                const int gr = row0 + MROW + m * 16 + (lane >> 4) * 4 + r;
                C[(size_t)gr * 1024 + gc] = acc[m][n][r];
            }
        }
}

// ---------------------------------------------------------------------------
// Launch.  Workspace (ws >= 80 MB, proven by round-0 layout):
//   0-16 KT | 16-32 VT | 32-48 kvbf -> Opart | 48-52 Qb | 52-56 wkvT
//  56-58 wqT | 58-60 woutT | 60-60.5 m_ws,l_ws | 64-68 qbf
// ---------------------------------------------------------------------------
extern "C" void kernel_launch(void* const* d_in, const int* in_sizes, int n_in,
                              void* d_out, int out_size, void* d_ws, size_t ws_size,
                              hipStream_t stream) {
    const float* query     = (const float*)d_in[0];
    const float* key_value = (const float*)d_in[1];
    const float* w_q       = (const float*)d_in[2];
    const float* w_kv      = (const float*)d_in[3];
    const float* w_out     = (const float*)d_in[4];
    float* out = (float*)d_out;

    char* ws = (char*)d_ws;
    const size_t MB = 1024 * 1024;
    u16*   KT    = (u16*)(ws);
    u16*   VT    = (u16*)(ws + 16 * MB);
    u16*   kvbf  = (u16*)(ws + 32 * MB);   // dead after qkvgemm
    float* Opart = (float*)(ws + 32 * MB); // written by attn
    u16*   Qb    = (u16*)(ws + 48 * MB);
    u16*   wkvT  = (u16*)(ws + 52 * MB);
    u16*   wqT   = (u16*)(ws + 56 * MB);
    u16*   woutT = (u16*)(ws + 58 * MB);
    float* m_wsp = (float*)(ws + 60 * MB);
    float* l_wsp = (float*)(ws + 60 * MB + 256 * 1024);
    u16*   qbf   = (u16*)(ws + 64 * MB);

    dim3 blk(256);

    // 1) weight transposes (swizzled) + activation casts
    wtrans_all<<<1024, blk, 0, stream>>>(w_q, w_kv, w_out, wqT, wkvT, woutT);
    cast_all<<<5120, blk, 0, stream>>>(query, key_value, qbf, kvbf);

    // 2) FUSED Q + KV projections, pure gload16 staging (m97 structure)
    qkvgemm<<<1280, blk, 0, stream>>>(qbf, kvbf, wqT, wkvT, Qb, KT, VT);

    // 3) split-K flash attention (round-8 proven kernel, 512 blocks)
    attn_mfma<<<dim3(KSPLIT * 256), blk, 0, stream>>>(
        Qb, KT, VT, Opart, m_wsp, l_wsp);

    // 4) output GEMM (fused split-K combine in A-staging)
    ogemm<<<dim3(8, 32), blk, 0, stream>>>(Opart, m_wsp, l_wsp, woutT, out);
}

// Round 13
// 166.879 us; speedup vs baseline: 1.4280x; 1.0454x over previous
//
#include <hip/hip_runtime.h>

// Problem constants (CompactCrossAttention)
#define Bb   2
#define QL   1024
#define KL   4096
#define Hh   1024
#define NH   16
#define HD   64

#define KSPLIT 2
#define CHUNK  (KL / KSPLIT)   // 2048 keys per block
#define NTT    (CHUNK / 64)    // 32 tiles of 64 keys

typedef unsigned short u16;
typedef __attribute__((ext_vector_type(8))) short bf16x8;     // MFMA A/B frag
typedef __attribute__((ext_vector_type(4))) float f32x4;      // 16x16 C/D frag
typedef __attribute__((ext_vector_type(16))) float f32x16;    // 32x32 C/D frag

#define QSCALE 0.1803368801111204f   // 0.125 * log2(e): scores in log2 domain
#define RTHR   11.0f                 // defer-max threshold (log2 units)

__device__ __forceinline__ u16 f2bf(float f) {
    union { float f; unsigned int u; } v; v.f = f;
    unsigned int r = (v.u + 0x7FFFu + ((v.u >> 16) & 1u)) >> 16;
    return (u16)r;
}

__device__ __forceinline__ unsigned int cvt_pk_bf16(float lo, float hi) {
    unsigned int r;
    asm("v_cvt_pk_bf16_f32 %0, %1, %2" : "=v"(r) : "v"(lo), "v"(hi));
    return r;
}

__device__ __forceinline__ float max3f(float a, float b, float c) {
    float r;
    asm("v_max3_f32 %0, %1, %2, %3" : "=v"(r) : "v"(a), "v"(b), "v"(c));
    return r;
}

// v_permlane32_swap_b32: new_a[l<32]=a[l], new_a[l>=32]=b[l-32];
//                        new_b[l<32]=a[l+32], new_b[l>=32]=b[l]
__device__ __forceinline__ void plane32swap(unsigned int& a, unsigned int& b) {
    asm volatile("v_permlane32_swap_b32 %0, %1" : "+v"(a), "+v"(b));
}

__device__ __forceinline__ void gload16(const void* g, void* l) {
    __builtin_amdgcn_global_load_lds(
        (const __attribute__((address_space(1))) void*)g,
        (__attribute__((address_space(3))) void*)l, 16, 0, 0);
}

// pack 8 fp32 -> 8 bf16 (uint4)
__device__ __forceinline__ uint4 pack8(const float4& f0, const float4& f1) {
    uint4 o;
    o.x = cvt_pk_bf16(f0.x, f0.y);
    o.y = cvt_pk_bf16(f0.z, f0.w);
    o.z = cvt_pk_bf16(f1.x, f1.y);
    o.w = cvt_pk_bf16(f1.z, f1.w);
    return o;
}

// ---------------------------------------------------------------------------
// PREP: weight transposes (swizzled) + activation casts, ONE launch.
// Blocks [0,256) w_q | [256,768) w_kv | [768,1024) w_out |
//        [1024,2048) query cast | [2048,6144) key_value cast.
// ---------------------------------------------------------------------------
__global__ __launch_bounds__(256) void prep_all(const float* __restrict__ wq,
                                                const float* __restrict__ wkv,
                                                const float* __restrict__ wout,
                                                const float* __restrict__ qact,
                                                const float* __restrict__ kvact,
                                                u16* __restrict__ wqT,
                                                u16* __restrict__ wkvT,
                                                u16* __restrict__ woutT,
                                                u16* __restrict__ qb,
                                                u16* __restrict__ kvb) {
    __shared__ float T[64][65];
    int bid = blockIdx.x;
    if (bid >= 1024) {
        bid -= 1024;
        const float* in; u16* out;
        if (bid < 1024) { in = qact;  out = qb;  }
        else            { in = kvact; out = kvb; bid -= 1024; }
        const size_t i = ((size_t)bid * 256 + threadIdx.x) * 8;
        float4 f0 = *reinterpret_cast<const float4*>(in + i);
        float4 f1 = *reinterpret_cast<const float4*>(in + i + 4);
        *reinterpret_cast<uint4*>(out + i) = pack8(f0, f1);
        return;
    }
    const float* in; u16* out; int C;
    if (bid < 256)      { in = wq;   out = wqT;   C = 1024; }
    else if (bid < 768) { in = wkv;  out = wkvT;  C = 2048; bid -= 256; }
    else                { in = wout; out = woutT; C = 1024; bid -= 768; }
    const int nc = C >> 6;
    const int c0 = (bid % nc) * 64;
    const int r0 = (bid / nc) * 64;
    const int t  = threadIdx.x;
    const int tx = t & 15, ty = t >> 4;
#pragma unroll
    for (int p = 0; p < 4; ++p) {
        const int r = ty + p * 16;
        float4 v = *reinterpret_cast<const float4*>(in + (size_t)(r0 + r) * C + c0 + tx * 4);
        T[r][tx * 4 + 0] = v.x; T[r][tx * 4 + 1] = v.y;
        T[r][tx * 4 + 2] = v.z; T[r][tx * 4 + 3] = v.w;
    }
    __syncthreads();
#pragma unroll
    for (int p = 0; p < 4; ++p) {
        const int c = ty + p * 16;
        const int n = c0 + c;
        ushort4 o;
        o.x = f2bf(T[tx * 4 + 0][c]); o.y = f2bf(T[tx * 4 + 1][c]);
        o.z = f2bf(T[tx * 4 + 2][c]); o.w = f2bf(T[tx * 4 + 3][c]);
        const int kb   = r0 + tx * 4;
        const int kout = (kb & ~63) | ((((kb >> 3) & 7) ^ (n & 7)) << 3) | (kb & 7);
        *reinterpret_cast<ushort4*>(out + (size_t)n * 1024 + kout) = o;
    }
}

// ---------------------------------------------------------------------------
// FUSED Q + KV projection GEMM — m97 structure (unchanged from round 12).
// ---------------------------------------------------------------------------
__global__ __launch_bounds__(256) void qkvgemm(const u16* __restrict__ Aq,
                                               const u16* __restrict__ Akv,
                                               const u16* __restrict__ wqT,
                                               const u16* __restrict__ wkvT,
                                               u16* __restrict__ Qb,
                                               u16* __restrict__ KT,
                                               u16* __restrict__ VT) {
    __shared__ u16 As[128 * 64];
    __shared__ u16 Bs[128 * 64];
    const int tid = threadIdx.x, lane = tid & 63, w = tid >> 6;
    const int wr = w >> 1, wc = w & 1;
    const int x7 = lane & 7;
    const int lrow = lane >> 3, lcol = (lane & 7) * 8;
    const int swcol = lcol ^ ((lrow & 7) << 3);   // A source granule XOR

    if (blockIdx.x < 1024) {
        const int id = blockIdx.x;
        const int sw = (id & 7) * 128 + (id >> 3);
        const int bx = sw % 16, by = sw / 16;
        const int row0 = by * 128, col0 = bx * 128;
        const int MROW = wr * 64;

        f32x4 acc[4][4];
#pragma unroll
        for (int m = 0; m < 4; ++m)
#pragma unroll
            for (int n = 0; n < 4; ++n) acc[m][n] = (f32x4){0.f, 0.f, 0.f, 0.f};

        auto stage = [&](int k0) {
            __syncthreads();
#pragma unroll
            for (int p = 0; p < 4; ++p) {
                const int base = w * 512 + p * 2048;
                const int row  = (base >> 6) + lrow;
                gload16(Akv + (size_t)(row0 + row) * 1024 + k0 + swcol, &As[base]);
                gload16(wkvT + (size_t)(col0 + row) * 1024 + k0 + lcol, &Bs[base]);
            }
            __syncthreads();
        };

        if (col0 < 1024) {
            for (int k0 = 0; k0 < 1024; k0 += 64) {
                stage(k0);
#pragma unroll
                for (int kk = 0; kk < 2; ++kk) {
                    bf16x8 af[4], bfr[4];
                    const int G = ((kk * 4 + (lane >> 4)) ^ x7) * 8;
#pragma unroll
                    for (int m = 0; m < 4; ++m)
                        af[m] = *reinterpret_cast<const bf16x8*>(
                            &As[(MROW + m * 16 + (lane & 15)) * 64 + G]);
#pragma unroll
                    for (int n = 0; n < 4; ++n)
                        bfr[n] = *reinterpret_cast<const bf16x8*>(
                            &Bs[(wc * 64 + n * 16 + (lane & 15)) * 64 + G]);
#pragma unroll
                    for (int m = 0; m < 4; ++m)
#pragma unroll
                        for (int n = 0; n < 4; ++n)
                            acc[m][n] = __builtin_amdgcn_mfma_f32_16x16x32_bf16(
                                bfr[n], af[m], acc[m][n], 0, 0, 0);
                }
            }
#pragma unroll
            for (int m = 0; m < 4; ++m) {
                const int gr  = row0 + MROW + m * 16 + (lane & 15);
                const int b   = gr >> 12;
                const int k   = gr & 4095;
                const int kt_i = k >> 6, k_in = k & 63;
#pragma unroll
                for (int n = 0; n < 4; ++n) {
                    const int gc0 = col0 + wc * 64 + n * 16 + (lane >> 4) * 4;
                    const int h   = gc0 >> 6, d0 = gc0 & 63;
                    u16* blob = KT + (((size_t)((b << 4) + h) * 64 + kt_i) << 9) * 8;
                    const int og = k_in * 8 + ((d0 >> 3) ^ (k_in & 7));
                    ushort4 pk;
                    pk.x = f2bf(acc[m][n][0]); pk.y = f2bf(acc[m][n][1]);
                    pk.z = f2bf(acc[m][n][2]); pk.w = f2bf(acc[m][n][3]);
                    *reinterpret_cast<ushort4*>(&blob[og * 8 + (d0 & 7)]) = pk;
                }
            }
        } else {
            for (int k0 = 0; k0 < 1024; k0 += 64) {
                stage(k0);
#pragma unroll
                for (int kk = 0; kk < 2; ++kk) {
                    bf16x8 af[4], bfr[4];
                    const int G = ((kk * 4 + (lane >> 4)) ^ x7) * 8;
#pragma unroll
                    for (int m = 0; m < 4; ++m)
                        af[m] = *reinterpret_cast<const bf16x8*>(
                            &As[(MROW + m * 16 + (lane & 15)) * 64 + G]);
#pragma unroll
                    for (int n = 0; n < 4; ++n)
                        bfr[n] = *reinterpret_cast<const bf16x8*>(
                            &Bs[(wc * 64 + n * 16 + (lane & 15)) * 64 + G]);
#pragma unroll
                    for (int m = 0; m < 4; ++m)
#pragma unroll
                        for (int n = 0; n < 4; ++n)
                            acc[m][n] = __builtin_amdgcn_mfma_f32_16x16x32_bf16(
                                af[m], bfr[n], acc[m][n], 0, 0, 0);
                }
            }
#pragma unroll
            for (int m = 0; m < 4; ++m) {
                const int gr0 = row0 + MROW + m * 16 + (lane >> 4) * 4;
                const int b   = gr0 >> 12;
                const int k   = gr0 & 4095;
                const int kt_i = k >> 6, k_in = k & 63;
#pragma unroll
                for (int n = 0; n < 4; ++n) {
                    const int gc = col0 + wc * 64 + n * 16 + (lane & 15);
                    const int h  = (gc & 1023) >> 6, d = gc & 63;
                    u16* blob = VT + (((size_t)((b << 4) + h) * 64 + kt_i) << 9) * 8;
                    const int og = d * 8 + ((k_in >> 3) ^ (d & 7));
                    ushort4 pk;
                    pk.x = f2bf(acc[m][n][0]); pk.y = f2bf(acc[m][n][1]);
                    pk.z = f2bf(acc[m][n][2]); pk.w = f2bf(acc[m][n][3]);
                    *reinterpret_cast<ushort4*>(&blob[og * 8 + (k_in & 7)]) = pk;
                }
            }
        }
    } else {
        const int id = blockIdx.x - 1024;
        const int sw = (id & 7) * 32 + (id >> 3);
        const int bx = sw % 8, by = sw / 8;
        const int row0 = by * 64, col0 = bx * 128;
        const int MROW = wr * 32;

        f32x4 acc[2][4];
#pragma unroll
        for (int m = 0; m < 2; ++m)
#pragma unroll
            for (int n = 0; n < 4; ++n) acc[m][n] = (f32x4){0.f, 0.f, 0.f, 0.f};

        for (int k0 = 0; k0 < 1024; k0 += 64) {
            __syncthreads();
#pragma unroll
            for (int p = 0; p < 2; ++p) {
                const int base = w * 512 + p * 2048;
                const int row  = (base >> 6) + lrow;
                gload16(Aq + (size_t)(row0 + row) * 1024 + k0 + swcol, &As[base]);
            }
#pragma unroll
            for (int p = 0; p < 4; ++p) {
                const int base = w * 512 + p * 2048;
                const int row  = (base >> 6) + lrow;
                gload16(wqT + (size_t)(col0 + row) * 1024 + k0 + lcol, &Bs[base]);
            }
            __syncthreads();
#pragma unroll
            for (int kk = 0; kk < 2; ++kk) {
                bf16x8 af[2], bfr[4];
                const int G = ((kk * 4 + (lane >> 4)) ^ x7) * 8;
#pragma unroll
                for (int m = 0; m < 2; ++m)
                    af[m] = *reinterpret_cast<const bf16x8*>(
                        &As[(MROW + m * 16 + (lane & 15)) * 64 + G]);
#pragma unroll
                for (int n = 0; n < 4; ++n)
                    bfr[n] = *reinterpret_cast<const bf16x8*>(
                        &Bs[(wc * 64 + n * 16 + (lane & 15)) * 64 + G]);
#pragma unroll
                for (int m = 0; m < 2; ++m)
#pragma unroll
                    for (int n = 0; n < 4; ++n)
                        acc[m][n] = __builtin_amdgcn_mfma_f32_16x16x32_bf16(
                            af[m], bfr[n], acc[m][n], 0, 0, 0);
            }
        }
#pragma unroll
        for (int m = 0; m < 2; ++m)
#pragma unroll
            for (int n = 0; n < 4; ++n) {
                const int gc = col0 + wc * 64 + n * 16 + (lane & 15);
#pragma unroll
                for (int r = 0; r < 4; ++r) {
                    const int gr = row0 + MROW + m * 16 + (lane >> 4) * 4 + r;
                    Qb[(size_t)gr * 1024 + gc] = f2bf(acc[m][n][r] * QSCALE);
                }
            }
    }
}

// ---------------------------------------------------------------------------
// Split-K bf16 flash attention v13: 32x32x16 MFMA + in-register P.
// Per wave: 32 q rows (q = lane&31; lane pair (l, l+32) shares q, splits keys).
// QK: S^T[key][q] = mfma(K_chunk, Q), 2 key-chunks x 4 d-chunks = 8 MFMA.
// Softmax: in-lane trees + 1 shfl_xor(32).  P: cvt_pk + permlane32_swap
// (no LDS).  PV: O[d][q] = mfma(V^T_chunk, P), 4 k-chunks x 2 d-chunks.
// Double-buffered gload_lds staging (R8 pattern), counted vmcnt(4).
// Grid: KSPLIT * B * NH * (QL/128) = 512 blocks, 256 threads.
// ---------------------------------------------------------------------------
__global__ __launch_bounds__(256, 2) void attn_mfma(const u16* __restrict__ Qb,
                                                    const u16* __restrict__ KT,
                                                    const u16* __restrict__ VT2,
                                                    float* __restrict__ Op,
                                                    float* __restrict__ m_ws,
                                                    float* __restrict__ l_ws) {
    __shared__ u16 Ks[2][4096];   // [key][slot*8], slot = gl ^ (key&7)
    __shared__ u16 Vs[2][4096];   // [d][slot*8],   slot = gl ^ (d&7)

    const int bid0 = blockIdx.x;
    const int bid  = (bid0 & 7) * 64 + (bid0 >> 3);   // XCD swizzle (512 blocks)
    const int qb   = bid & 7;
    const int h    = (bid >> 3) & 15;
    const int b    = (bid >> 7) & 1;
    const int c    = bid >> 8;
    const int tid  = threadIdx.x;
    const int lane = tid & 63;
    const int w    = tid >> 6;
    const int q    = lane & 31;       // this lane's q column
    const int hl   = lane >> 5;       // half (k-element group)
    const int l7   = lane & 7;
    const int q0   = qb * 128;
    const int bh   = b * NH + h;

    // Q B-frags: qa[dc](lane,e) = Q[q][d = dc*16 + hl*8 + e]
    bf16x8 qa[4];
    {
        const u16* qsrc = Qb + (size_t)(b * QL + q0 + w * 32 + q) * Hh
                          + h * HD + hl * 8;
#pragma unroll
        for (int dc = 0; dc < 4; ++dc)
            qa[dc] = *reinterpret_cast<const bf16x8*>(qsrc + dc * 16);
    }
    asm volatile("s_waitcnt vmcnt(0)" ::: "memory");

    float m_i = -1e30f, l_i = 0.f;
    f32x16 accO[2];
#pragma unroll
    for (int d2 = 0; d2 < 2; ++d2)
#pragma unroll
        for (int r = 0; r < 16; ++r) accO[d2][r] = 0.f;

    // hoisted LDS addressing: off[j] = slot offset for granule-pair j
    const u16* Kb0 = &Ks[0][q * 64];
    const u16* Vb0 = &Vs[0][q * 64];
    int off[4];
#pragma unroll
    for (int j = 0; j < 4; ++j) off[j] = (((j * 2 + hl) ^ l7) << 3);

    // staging pointers (R8 pattern; blob format unchanged)
    const size_t tb0 = ((size_t)bh * 64 + c * NTT) * 4096;
    const u16* kpt = KT  + tb0 + (size_t)(w * 64 + lane) * 8 + 1024;
    const u16* vpt = VT2 + tb0 + (size_t)(w * 64 + lane) * 8 + 1024;
    u16* kdst[2] = { &Ks[0][w * 512], &Ks[1][w * 512] };
    u16* vdst[2] = { &Vs[0][w * 512], &Vs[1][w * 512] };

    gload16(kpt - 1024, kdst[0]);
    gload16(kpt + 1024, kdst[0] + 2048);
    gload16(vpt - 1024, vdst[0]);
    gload16(vpt + 1024, vdst[0] + 2048);

    auto tile = [&](int CUR, int t) {
        __builtin_amdgcn_s_barrier();
        if (t + 1 < NTT) {
            kpt += 4096; vpt += 4096;
            gload16(kpt - 1024, kdst[CUR ^ 1]);
            gload16(kpt + 1024, kdst[CUR ^ 1] + 2048);
            gload16(vpt - 1024, vdst[CUR ^ 1]);
            gload16(vpt + 1024, vdst[CUR ^ 1] + 2048);
            asm volatile("s_waitcnt vmcnt(4)" ::: "memory");
        } else {
            asm volatile("s_waitcnt vmcnt(0)" ::: "memory");
        }
        __builtin_amdgcn_sched_barrier(0);
        __builtin_amdgcn_s_barrier();

        // QK^T: sc[kc][reg] = S[key = kc*32 + (reg&3)+8*(reg>>2)+4*hl][q]
        f32x16 sc[2];
        __builtin_amdgcn_s_setprio(1);
#pragma unroll
        for (int kc = 0; kc < 2; ++kc) {
            f32x16 z;
#pragma unroll
            for (int r = 0; r < 16; ++r) z[r] = 0.f;
#pragma unroll
            for (int dc = 0; dc < 4; ++dc) {
                bf16x8 kf = *reinterpret_cast<const bf16x8*>(
                    Kb0 + CUR * 4096 + kc * 2048 + off[dc]);
                z = __builtin_amdgcn_mfma_f32_32x32x16_bf16(kf, qa[dc], z, 0, 0, 0);
            }
            sc[kc] = z;
        }
        __builtin_amdgcn_s_setprio(0);

        // max over this lane's 32 scores, then combine lane pair (xor 32)
        float mx = max3f(sc[0][0], sc[0][1], sc[0][2]);
#pragma unroll
        for (int i = 3; i + 1 < 32; i += 2)
            mx = max3f(mx, sc[i >> 4][i & 15], sc[(i + 1) >> 4][(i + 1) & 15]);
        mx = fmaxf(mx, sc[1][15]);
        mx = fmaxf(mx, __shfl_xor(mx, 32));

        if (__any(mx > m_i + RTHR)) {          // defer-max
            const float mnew = fmaxf(m_i, mx);
            const float al   = exp2f(m_i - mnew);
            m_i = mnew;
            l_i *= al;
#pragma unroll
            for (int d2 = 0; d2 < 2; ++d2)
#pragma unroll
                for (int r = 0; r < 16; ++r) accO[d2][r] *= al;
        }
#pragma unroll
        for (int kc = 0; kc < 2; ++kc)
#pragma unroll
            for (int r = 0; r < 16; ++r) sc[kc][r] = exp2f(sc[kc][r] - m_i);

        // l: in-lane pairwise sum + cross-half shfl
        {
            float p0 = sc[0][0], p1 = sc[0][1], p2 = sc[0][2], p3 = sc[0][3];
#pragma unroll
            for (int i = 4; i < 16; i += 4) {
                p0 += sc[0][i];     p1 += sc[0][i + 1];
                p2 += sc[0][i + 2]; p3 += sc[0][i + 3];
            }
#pragma unroll
            for (int i = 0; i < 16; i += 4) {
                p0 += sc[1][i];     p1 += sc[1][i + 1];
                p2 += sc[1][i + 2]; p3 += sc[1][i + 3];
            }
            float sum = (p0 + p1) + (p2 + p3);
            sum += __shfl_xor(sum, 32);
            l_i += sum;
        }

        // PV: per k-chunk kk, build P B-frag in registers via permlane32_swap
        __builtin_amdgcn_s_setprio(1);
#pragma unroll
        for (int kk = 0; kk < 4; ++kk) {
            const int kc  = kk >> 1;
            const int rb  = (kk & 1) * 8;
            unsigned int X0 = cvt_pk_bf16(sc[kc][rb + 0], sc[kc][rb + 1]);
            unsigned int X1 = cvt_pk_bf16(sc[kc][rb + 2], sc[kc][rb + 3]);
            unsigned int Y0 = cvt_pk_bf16(sc[kc][rb + 4], sc[kc][rb + 5]);
            unsigned int Y1 = cvt_pk_bf16(sc[kc][rb + 6], sc[kc][rb + 7]);
            plane32swap(X0, Y0);   // X0 -> words 0, Y0 -> word 2
            plane32swap(X1, Y1);   // X1 -> word 1, Y1 -> word 3
            uint4 wv = make_uint4(X0, X1, Y0, Y1);
            bf16x8 pf;
            __builtin_memcpy(&pf, &wv, 16);
            bf16x8 vf0 = *reinterpret_cast<const bf16x8*>(
                Vb0 + CUR * 4096 + off[kk]);
            bf16x8 vf1 = *reinterpret_cast<const bf16x8*>(
                Vb0 + CUR * 4096 + 2048 + off[kk]);
            accO[0] = __builtin_amdgcn_mfma_f32_32x32x16_bf16(vf0, pf, accO[0], 0, 0, 0);
            accO[1] = __builtin_amdgcn_mfma_f32_32x32x16_bf16(vf1, pf, accO[1], 0, 0, 0);
        }
        __builtin_amdgcn_s_setprio(0);
    };

    for (int t = 0; t < NTT; t += 2) {
        tile(0, t);
        tile(1, t + 1);
    }

    // epilogue: unnormalized O (float4 stores) + per-row m,l
    float* opc = Op + (size_t)c * ((size_t)Bb * QL * Hh)
                 + (size_t)(b * QL + q0 + w * 32 + q) * Hh + h * HD;
#pragma unroll
    for (int d2 = 0; d2 < 2; ++d2) {
#pragma unroll
        for (int b2 = 0; b2 < 4; ++b2) {
            float4 v = make_float4(accO[d2][4 * b2 + 0], accO[d2][4 * b2 + 1],
                                   accO[d2][4 * b2 + 2], accO[d2][4 * b2 + 3]);
            *reinterpret_cast<float4*>(opc + d2 * 32 + b2 * 8 + hl * 4) = v;
        }
    }
    if (hl == 0) {
        const int idx = ((c * Bb + b) * NH + h) * QL + q0 + w * 32 + q;
        m_ws[idx] = m_i;
        l_ws[idx] = l_i;
    }
}

// ---------------------------------------------------------------------------
// Output GEMM with FUSED split-K combine in A-staging.  BMT=64.
// ---------------------------------------------------------------------------
__global__ __launch_bounds__(256) void ogemm(const float* __restrict__ Op,
                                             const float* __restrict__ m_ws,
                                             const float* __restrict__ l_ws,
                                             const u16* __restrict__ Bt,
                                             float* __restrict__ C) {
    __shared__ u16 As[64 * 64];
    __shared__ u16 Bs[128 * 64];
    const int nwg = gridDim.x * gridDim.y;
    const int id  = blockIdx.y * gridDim.x + blockIdx.x;
    const int sw  = (id & 7) * (nwg >> 3) + (id >> 3);
    const int bx  = sw % gridDim.x, by = sw / gridDim.x;
    const int tid = threadIdx.x, lane = tid & 63, w = tid >> 6;
    const int wr = w >> 1, wc = w & 1;
    const int row0 = by * 64, col0 = bx * 128;
    const int MROW = wr * 32;
    const int x7   = lane & 7;

    f32x4 acc[2][4];
#pragma unroll
    for (int m = 0; m < 2; ++m)
#pragma unroll
        for (int n = 0; n < 4; ++n) acc[m][n] = (f32x4){0.f, 0.f, 0.f, 0.f};

    const int lrow = lane >> 3, lcol = (lane & 7) * 8;
    const int arow = tid >> 3, acol8 = (tid & 7) * 8;
    const int aphys = acol8 ^ ((arow & 7) << 3);

    for (int k0 = 0; k0 < 1024; k0 += 64) {
        __syncthreads();
        const int h_ = k0 >> 6;   // uniform per step
#pragma unroll
        for (int p = 0; p < 2; ++p) {
            const int r    = p * 32 + arow;
            const int grow = row0 + r;
            const int b_   = grow >> 10, q_ = grow & 1023;
            const int idx  = (((b_ << 4) + h_) << 10) + q_;
            const float m0 = m_ws[idx], m1 = m_ws[idx + 32768];
            const float l0 = l_ws[idx], l1 = l_ws[idx + 32768];
            const float ms = fmaxf(m0, m1);
            float a0 = exp2f(m0 - ms), a1 = exp2f(m1 - ms);
            const float inv = 1.f / (l0 * a0 + l1 * a1);
            a0 *= inv; a1 *= inv;
            const float* o0 = Op + (size_t)grow * 1024 + k0 + acol8;
            const float* o1 = o0 + (size_t)Bb * QL * Hh;
            float4 x0 = *reinterpret_cast<const float4*>(o0);
            float4 x1 = *reinterpret_cast<const float4*>(o0 + 4);
            float4 y0 = *reinterpret_cast<const float4*>(o1);
            float4 y1 = *reinterpret_cast<const float4*>(o1 + 4);
            float4 f0 = make_float4(x0.x * a0 + y0.x * a1, x0.y * a0 + y0.y * a1,
                                    x0.z * a0 + y0.z * a1, x0.w * a0 + y0.w * a1);
            float4 f1 = make_float4(x1.x * a0 + y1.x * a1, x1.y * a0 + y1.y * a1,
                                    x1.z * a0 + y1.z * a1, x1.w * a0 + y1.w * a1);
            *reinterpret_cast<uint4*>(&As[r * 64 + aphys]) = pack8(f0, f1);
        }
#pragma unroll
        for (int p = 0; p < 4; ++p) {
            const int base = w * 512 + p * 2048;
            const int row  = (base >> 6) + lrow;
            gload16(Bt + (size_t)(col0 + row) * 1024 + k0 + lcol, &Bs[base]);
        }
        __syncthreads();
#pragma unroll
        for (int kk = 0; kk < 2; ++kk) {
            bf16x8 af[2], bfr[4];
            const int G = ((kk * 4 + (lane >> 4)) ^ x7) * 8;
#pragma unroll
            for (int m = 0; m < 2; ++m)
                af[m] = *reinterpret_cast<const bf16x8*>(
                    &As[(MROW + m * 16 + (lane & 15)) * 64 + G]);
#pragma unroll
            for (int n = 0; n < 4; ++n)
                bfr[n] = *reinterpret_cast<const bf16x8*>(
                    &Bs[(wc * 64 + n * 16 + (lane & 15)) * 64 + G]);
#pragma unroll
            for (int m = 0; m < 2; ++m)
#pragma unroll
                for (int n = 0; n < 4; ++n)
                    acc[m][n] = __builtin_amdgcn_mfma_f32_16x16x32_bf16(
                        af[m], bfr[n], acc[m][n], 0, 0, 0);
        }
    }
#pragma unroll
    for (int m = 0; m < 2; ++m)
#pragma unroll
        for (int n = 0; n < 4; ++n) {
            const int gc = col0 + wc * 64 + n * 16 + (lane & 15);
#pragma unroll
            for (int r = 0; r < 4; ++r) {
                const int gr = row0 + MROW + m * 16 + (lane >> 4) * 4 + r;
                C[(size_t)gr * 1024 + gc] = acc[m][n][r];
            }
        }
}

// ---------------------------------------------------------------------------
// Launch.  Workspace (ws >= 80 MB):
//   0-16 KT | 16-32 VT | 32-48 kvbf -> Opart | 48-52 Qb | 52-56 wkvT
//  56-58 wqT | 58-60 woutT | 60-60.5 m_ws,l_ws | 64-68 qbf
// ---------------------------------------------------------------------------
extern "C" void kernel_launch(void* const* d_in, const int* in_sizes, int n_in,
                              void* d_out, int out_size, void* d_ws, size_t ws_size,
                              hipStream_t stream) {
    const float* query     = (const float*)d_in[0];
    const float* key_value = (const float*)d_in[1];
    const float* w_q       = (const float*)d_in[2];
    const float* w_kv      = (const float*)d_in[3];
    const float* w_out     = (const float*)d_in[4];
    float* out = (float*)d_out;

    char* ws = (char*)d_ws;
    const size_t MB = 1024 * 1024;
    u16*   KT    = (u16*)(ws);
    u16*   VT    = (u16*)(ws + 16 * MB);
    u16*   kvbf  = (u16*)(ws + 32 * MB);   // dead after qkvgemm
    float* Opart = (float*)(ws + 32 * MB); // written by attn
    u16*   Qb    = (u16*)(ws + 48 * MB);
    u16*   wkvT  = (u16*)(ws + 52 * MB);
    u16*   wqT   = (u16*)(ws + 56 * MB);
    u16*   woutT = (u16*)(ws + 58 * MB);
    float* m_wsp = (float*)(ws + 60 * MB);
    float* l_wsp = (float*)(ws + 60 * MB + 256 * 1024);
    u16*   qbf   = (u16*)(ws + 64 * MB);

    dim3 blk(256);

    // 1) weight transposes (swizzled) + activation casts, one launch
    prep_all<<<6144, blk, 0, stream>>>(w_q, w_kv, w_out, query, key_value,
                                       wqT, wkvT, woutT, qbf, kvbf);

    // 2) FUSED Q + KV projections (m97 structure)
    qkvgemm<<<1280, blk, 0, stream>>>(qbf, kvbf, wqT, wkvT, Qb, KT, VT);

    // 3) split-K flash attention (32x32 MFMA, in-register P)
    attn_mfma<<<dim3(KSPLIT * 256), blk, 0, stream>>>(
        Qb, KT, VT, Opart, m_wsp, l_wsp);

    // 4) output GEMM (fused split-K combine in A-staging)
    ogemm<<<dim3(8, 32), blk, 0, stream>>>(Opart, m_wsp, l_wsp, woutT, out);
}